// Round 1
// baseline (177.314 us; speedup 1.0000x reference)
//
#include <hip/hip_runtime.h>
#include <math.h>

#define E_DIM 256
#define H_DIM 128
#define NQv 8
#define QEDv 64
#define HYPv 64
#define NAv 14
#define NAGv 8
#define BSv 4096
#define G3v 384
#define W2COL 32768   // H*H*HEADS

#define OUT_H_OFF 458752
#define OUT_RQ_OFF 983040
#define WS_WEFF 0
#define WS_QPHI 16384

// ---------------- K0: W_eff = merger-softmax-folded hypernet output ----------
// prev == ones  =>  hh[j] = relu(sum_i hyp_w1[i][j] + b1[j])  (sample-independent)
// W_in[i][o] = hh . hyp_w2[:,i*256+o] + b2[...]; W_eff folds softmax over heads.
__global__ __launch_bounds__(256) void k_weff(
    const float* __restrict__ hyp_w1, const float* __restrict__ hyp_b1,
    const float* __restrict__ hyp_w2, const float* __restrict__ hyp_b2,
    const float* __restrict__ merger_w, float* __restrict__ weff) {
  __shared__ float hh[HYPv];
  __shared__ float part[4][2][64];
  int t = threadIdx.x;
  if (t < HYPv) {
    float s = hyp_b1[t];
#pragma unroll
    for (int i = 0; i < NQv; ++i) s += hyp_w1[i * HYPv + t];
    hh[t] = fmaxf(s, 0.f);
  }
  __syncthreads();
  int w = t >> 6, lane = t & 63;
  int i = blockIdx.x >> 1;
  int cbase = (blockIdx.x & 1) * 64;
  int o0 = i * 256 + cbase + lane;
  float a0 = 0.f, a1 = 0.f;
#pragma unroll
  for (int jj = 0; jj < 16; ++jj) {
    int j = w * 16 + jj;
    float hj = hh[j];
    a0 = fmaf(hj, hyp_w2[j * W2COL + o0], a0);
    a1 = fmaf(hj, hyp_w2[j * W2COL + o0 + 128], a1);
  }
  part[w][0][lane] = a0;
  part[w][1][lane] = a1;
  __syncthreads();
  if (t < 64) {
    int c = cbase + t;
    float h0 = part[0][0][t] + part[1][0][t] + part[2][0][t] + part[3][0][t]
               + hyp_b2[i * 256 + c];
    float h1 = part[0][1][t] + part[1][1][t] + part[2][1][t] + part[3][1][t]
               + hyp_b2[i * 256 + c + 128];
    float m0 = merger_w[c], m1 = merger_w[128 + c];
    float mx = fmaxf(m0, m1);
    float e0 = expf(m0 - mx), e1 = expf(m1 - mx);
    weff[i * 128 + c] = (e0 * h0 + e1 * h1) / (e0 + e1);
  }
}

// ---------------- K1: fused fc1 -> emb(W_eff) -> GRU, 16 samples / block -----
__global__ __launch_bounds__(256) void k_rnn(
    const float* __restrict__ inp, const float* __restrict__ hprev,
    const float* __restrict__ fc1_w, const float* __restrict__ fc1_b,
    const float* __restrict__ weff,
    const float* __restrict__ gru_wi, const float* __restrict__ gru_wh,
    const float* __restrict__ gru_bi, const float* __restrict__ gru_bh,
    float* __restrict__ h_out) {
  const int S = 16;
  __shared__ float x_s[S][H_DIM];     // fc1 output (relu)
  __shared__ float x2_s[S][H_DIM];    // emb output (relu)
  __shared__ float A_s[S][256];       // ir+hr (g<128), iz+hz (g<256)
  __shared__ float inn_s[S][H_DIM];   // gi for g in [256,384)
  __shared__ float hn_s[S][H_DIM];    // gh for g in [256,384)
  int t = threadIdx.x;
  int b0 = blockIdx.x * S;
  int c = t & 127, sh = t >> 7;
  int sb = sh * 8;
  int sbu = __builtin_amdgcn_readfirstlane(sb);  // wave-uniform -> scalar loads

  // ---- fc1 + relu: x = relu(in @ fc1_w + b). inputs read via scalar pipe.
  {
    const float* inbase = inp + (size_t)(b0 + sbu) * E_DIM;
    float acc[8];
    float bv = fc1_b[c];
#pragma unroll
    for (int s = 0; s < 8; ++s) acc[s] = bv;
#pragma unroll 4
    for (int e = 0; e < E_DIM; ++e) {
      float wv = fc1_w[e * H_DIM + c];
#pragma unroll
      for (int s = 0; s < 8; ++s)
        acc[s] = fmaf(inbase[s * E_DIM + e], wv, acc[s]);
    }
#pragma unroll
    for (int s = 0; s < 8; ++s) x_s[sbu + s][c] = fmaxf(acc[s], 0.f);
  }
  __syncthreads();

  // ---- emb: x2 = relu(x @ W_eff)
  {
    float acc[8];
#pragma unroll
    for (int s = 0; s < 8; ++s) acc[s] = 0.f;
#pragma unroll 4
    for (int i = 0; i < H_DIM; ++i) {
      float wv = weff[i * H_DIM + c];
#pragma unroll
      for (int s = 0; s < 8; ++s)
        acc[s] = fmaf(x_s[sbu + s][i], wv, acc[s]);
    }
#pragma unroll
    for (int s = 0; s < 8; ++s) x2_s[sbu + s][c] = fmaxf(acc[s], 0.f);
  }
  __syncthreads();

  // ---- GRU part 1: g = t in [0,256) (r,z rows), all 16 samples, gi+gh summed
  {
    int g = t;
    float ai[S];
    float bsum = gru_bi[g] + gru_bh[g];
#pragma unroll
    for (int s = 0; s < S; ++s) ai[s] = bsum;
    const float4* wi4 = (const float4*)(gru_wi + (size_t)g * H_DIM);
    const float4* wh4 = (const float4*)(gru_wh + (size_t)g * H_DIM);
    for (int k4 = 0; k4 < H_DIM / 4; ++k4) {
      float4 wi = wi4[k4], wh = wh4[k4];
#pragma unroll
      for (int s = 0; s < S; ++s) {
        float4 xv = *(const float4*)&x2_s[s][k4 * 4];
        float4 hv = *(const float4*)&hprev[(size_t)(b0 + s) * H_DIM + k4 * 4];
        ai[s] = fmaf(xv.x, wi.x, ai[s]); ai[s] = fmaf(xv.y, wi.y, ai[s]);
        ai[s] = fmaf(xv.z, wi.z, ai[s]); ai[s] = fmaf(xv.w, wi.w, ai[s]);
        ai[s] = fmaf(hv.x, wh.x, ai[s]); ai[s] = fmaf(hv.y, wh.y, ai[s]);
        ai[s] = fmaf(hv.z, wh.z, ai[s]); ai[s] = fmaf(hv.w, wh.w, ai[s]);
      }
    }
#pragma unroll
    for (int s = 0; s < S; ++s) A_s[s][g] = ai[s];
  }

  // ---- GRU part 2: g = 256 + c (n rows), each sh-half does 8 samples
  {
    int g = 256 + c;
    float ai[8], ah[8];
    float bi = gru_bi[g], bh = gru_bh[g];
#pragma unroll
    for (int s = 0; s < 8; ++s) { ai[s] = bi; ah[s] = bh; }
    const float4* wi4 = (const float4*)(gru_wi + (size_t)g * H_DIM);
    const float4* wh4 = (const float4*)(gru_wh + (size_t)g * H_DIM);
    for (int k4 = 0; k4 < H_DIM / 4; ++k4) {
      float4 wi = wi4[k4], wh = wh4[k4];
#pragma unroll
      for (int s = 0; s < 8; ++s) {
        float4 xv = *(const float4*)&x2_s[sbu + s][k4 * 4];
        float4 hv = *(const float4*)&hprev[(size_t)(b0 + sbu + s) * H_DIM + k4 * 4];
        ai[s] = fmaf(xv.x, wi.x, ai[s]); ai[s] = fmaf(xv.y, wi.y, ai[s]);
        ai[s] = fmaf(xv.z, wi.z, ai[s]); ai[s] = fmaf(xv.w, wi.w, ai[s]);
        ah[s] = fmaf(hv.x, wh.x, ah[s]); ah[s] = fmaf(hv.y, wh.y, ah[s]);
        ah[s] = fmaf(hv.z, wh.z, ah[s]); ah[s] = fmaf(hv.w, wh.w, ah[s]);
      }
    }
#pragma unroll
    for (int s = 0; s < 8; ++s) { inn_s[sbu + s][c] = ai[s]; hn_s[sbu + s][c] = ah[s]; }
  }
  __syncthreads();

  // ---- gates + h
#pragma unroll
  for (int si = 0; si < 8; ++si) {
    int s = sb + si;
    float r = 1.f / (1.f + expf(-A_s[s][c]));
    float z = 1.f / (1.f + expf(-A_s[s][128 + c]));
    float n = tanhf(inn_s[s][c] + r * hn_s[s][c]);
    float hpv = hprev[(size_t)(b0 + s) * H_DIM + c];
    h_out[(size_t)(b0 + s) * H_DIM + c] = (1.f - z) * n + z * hpv;
  }
}

// ---------------- K2: quantile embedding q_phi = relu(cos @ phi_w + b) ------
__global__ __launch_bounds__(128) void k_qphi(
    const float* __restrict__ rnd, const float* __restrict__ phi_w,
    const float* __restrict__ phi_b, float* __restrict__ qphi,
    float* __restrict__ rq_out) {
  const int R = 8;
  __shared__ float cos_s[R][QEDv];
  int t = threadIdx.x;
  int r0 = blockIdx.x * R;
#pragma unroll
  for (int ii = 0; ii < R * QEDv / 128; ++ii) {
    int idx = t + ii * 128;
    int r = idx >> 6, f = idx & 63;
    cos_s[r][f] = cosf(3.14159265358979323846f * (float)f * rnd[r0 + r]);
  }
  if (t < R) rq_out[r0 + t] = rnd[r0 + t];
  __syncthreads();
  float acc[R];
  float bv = phi_b[t];
#pragma unroll
  for (int r = 0; r < R; ++r) acc[r] = bv;
#pragma unroll 4
  for (int f = 0; f < QEDv; ++f) {
    float wv = phi_w[f * H_DIM + t];
#pragma unroll
    for (int r = 0; r < R; ++r) acc[r] = fmaf(cos_s[r][f], wv, acc[r]);
  }
#pragma unroll
  for (int r = 0; r < R; ++r)
    qphi[(size_t)(r0 + r) * H_DIM + t] = fmaxf(acc[r], 0.f);
}

// ---------------- K3: q = (h (x) q_phi) @ fc2_w + b, sort over quantiles ----
__global__ __launch_bounds__(256) void k_qsort(
    const float* __restrict__ h_in, const float* __restrict__ qphi,
    const float* __restrict__ fc2_w, const float* __restrict__ fc2_b,
    float* __restrict__ q_out) {
  const int BB = 16;
  __shared__ float h_s[BB][H_DIM + 4];
  __shared__ float qp_s[BB][H_DIM + 4];
  __shared__ float w_s[NAv][H_DIM + 1];
  __shared__ float b_s[NAv];
  int t = threadIdx.x;
  int b0 = blockIdx.x * BB;
  {
    const float4* hs = (const float4*)(h_in + (size_t)b0 * H_DIM);
    for (int idx = t; idx < BB * H_DIM / 4; idx += 256) {
      int row = idx >> 5, col = idx & 31;
      ((float4*)&h_s[row][0])[col] = hs[idx];
    }
    const float4* qs = (const float4*)(qphi + (size_t)(b0 / NAGv) * NQv * H_DIM);
    for (int idx = t; idx < BB * H_DIM / 4; idx += 256) {
      int row = idx >> 5, col = idx & 31;
      ((float4*)&qp_s[row][0])[col] = qs[idx];
    }
    for (int idx = t; idx < H_DIM * NAv; idx += 256) {
      int cc = idx / NAv, aa = idx - cc * NAv;
      w_s[aa][cc] = fc2_w[idx];
    }
    if (t < NAv) b_s[t] = fc2_b[t];
  }
  __syncthreads();
  if (t >= BB * NAv) return;
  int bl = t / NAv, a = t - bl * NAv;
  int glb = (bl >> 3) << 3;  // local q_phi row base (two agent-groups per block)
  float qv[NQv];
  float bias = b_s[a];
#pragma unroll
  for (int k = 0; k < NQv; ++k) qv[k] = bias;
  for (int cc = 0; cc < H_DIM; ++cc) {
    float hw = h_s[bl][cc] * w_s[a][cc];
#pragma unroll
    for (int k = 0; k < NQv; ++k)
      qv[k] = fmaf(hw, qp_s[glb + k][cc], qv[k]);
  }
  // Batcher odd-even mergesort, 8 elements, 19 compare-exchanges
#define CE(i, j) { float lo_ = fminf(qv[i], qv[j]); float hi_ = fmaxf(qv[i], qv[j]); qv[i] = lo_; qv[j] = hi_; }
  CE(0,1) CE(2,3) CE(4,5) CE(6,7)
  CE(0,2) CE(1,3) CE(4,6) CE(5,7)
  CE(1,2) CE(5,6)
  CE(0,4) CE(1,5) CE(2,6) CE(3,7)
  CE(2,4) CE(3,5)
  CE(1,2) CE(3,4) CE(5,6)
#undef CE
  float4* o4 = (float4*)(q_out + (size_t)((b0 + bl) * NAv + a) * NQv);
  o4[0] = make_float4(qv[0], qv[1], qv[2], qv[3]);
  o4[1] = make_float4(qv[4], qv[5], qv[6], qv[7]);
}

extern "C" void kernel_launch(void* const* d_in, const int* in_sizes, int n_in,
                              void* d_out, int out_size, void* d_ws, size_t ws_size,
                              hipStream_t stream) {
  (void)in_sizes; (void)n_in; (void)out_size; (void)ws_size;
  const float* inp      = (const float*)d_in[0];
  const float* hidden   = (const float*)d_in[1];
  const float* rnd      = (const float*)d_in[2];
  const float* fc1_w    = (const float*)d_in[3];
  const float* fc1_b    = (const float*)d_in[4];
  const float* hyp_w1   = (const float*)d_in[5];
  const float* hyp_b1   = (const float*)d_in[6];
  const float* hyp_w2   = (const float*)d_in[7];
  const float* hyp_b2   = (const float*)d_in[8];
  const float* merger_w = (const float*)d_in[9];
  const float* gru_wi   = (const float*)d_in[10];
  const float* gru_wh   = (const float*)d_in[11];
  const float* gru_bi   = (const float*)d_in[12];
  const float* gru_bh   = (const float*)d_in[13];
  const float* phi_w    = (const float*)d_in[14];
  const float* phi_b    = (const float*)d_in[15];
  const float* fc2_w    = (const float*)d_in[16];
  const float* fc2_b    = (const float*)d_in[17];
  float* out  = (float*)d_out;
  float* ws   = (float*)d_ws;
  float* weff = ws + WS_WEFF;    // 128*128 f32
  float* qphi = ws + WS_QPHI;    // 4096*128 f32
  float* h_out = out + OUT_H_OFF;

  k_weff<<<dim3(256), dim3(256), 0, stream>>>(hyp_w1, hyp_b1, hyp_w2, hyp_b2,
                                              merger_w, weff);
  k_qphi<<<dim3(512), dim3(128), 0, stream>>>(rnd, phi_w, phi_b, qphi,
                                              out + OUT_RQ_OFF);
  k_rnn<<<dim3(256), dim3(256), 0, stream>>>(inp, hidden, fc1_w, fc1_b, weff,
                                             gru_wi, gru_wh, gru_bi, gru_bh,
                                             h_out);
  k_qsort<<<dim3(256), dim3(256), 0, stream>>>(h_out, qphi, fc2_w, fc2_b, out);
}

// Round 2
// 126.213 us; speedup vs baseline: 1.4049x; 1.4049x over previous
//
#include <hip/hip_runtime.h>
#include <math.h>

typedef __attribute__((ext_vector_type(8))) short short8;
typedef __attribute__((ext_vector_type(4))) float floatx4;

#define E_DIM 256
#define H_DIM 128
#define NQv 8
#define QEDv 64
#define HYPv 64
#define NAv 14
#define NAGv 8
#define W2COL 32768   // H*H*HEADS

#define OUT_H_OFF 458752
#define OUT_RQ_OFF 983040
#define WS_WEFF 0
#define WS_QPHI 16384
#define WS_PACK 540672          // float offset of packed bf16 weights
// packed frag index bases (frag = 64 lanes x 8 bf16)
#define FB_W1  0                // fc1:  8kt x 8nt  -> 4096 frags
#define FB_WE  4096             // weff: 4kt x 8nt  -> 2048 frags
#define FB_WI  6144             // gru_wi^T: 4kt x 24nt -> 6144 frags
#define FB_WH  12288            // gru_wh^T: 4kt x 24nt -> 6144 frags
#define FRAGS_TOTAL 18432

__device__ __forceinline__ unsigned short f2bf(float x) {
  unsigned u = __builtin_bit_cast(unsigned, x);
  u += 0x7FFFu + ((u >> 16) & 1u);
  return (unsigned short)(u >> 16);
}

// ---------------- K0: W_eff = merger-softmax-folded hypernet output ----------
__global__ __launch_bounds__(256) void k_weff(
    const float* __restrict__ hyp_w1, const float* __restrict__ hyp_b1,
    const float* __restrict__ hyp_w2, const float* __restrict__ hyp_b2,
    const float* __restrict__ merger_w, float* __restrict__ weff) {
  __shared__ float hh[HYPv];
  __shared__ float part[4][2][64];
  int t = threadIdx.x;
  if (t < HYPv) {
    float s = hyp_b1[t];
#pragma unroll
    for (int i = 0; i < NQv; ++i) s += hyp_w1[i * HYPv + t];
    hh[t] = fmaxf(s, 0.f);
  }
  __syncthreads();
  int w = t >> 6, lane = t & 63;
  int i = blockIdx.x >> 1;
  int cbase = (blockIdx.x & 1) * 64;
  int o0 = i * 256 + cbase + lane;
  float a0 = 0.f, a1 = 0.f;
#pragma unroll
  for (int jj = 0; jj < 16; ++jj) {
    int j = w * 16 + jj;
    float hj = hh[j];
    a0 = fmaf(hj, hyp_w2[j * W2COL + o0], a0);
    a1 = fmaf(hj, hyp_w2[j * W2COL + o0 + 128], a1);
  }
  part[w][0][lane] = a0;
  part[w][1][lane] = a1;
  __syncthreads();
  if (t < 64) {
    int c = cbase + t;
    float h0 = part[0][0][t] + part[1][0][t] + part[2][0][t] + part[3][0][t]
               + hyp_b2[i * 256 + c];
    float h1 = part[0][1][t] + part[1][1][t] + part[2][1][t] + part[3][1][t]
               + hyp_b2[i * 256 + c + 128];
    float m0 = merger_w[c], m1 = merger_w[128 + c];
    float mx = fmaxf(m0, m1);
    float e0 = expf(m0 - mx), e1 = expf(m1 - mx);
    weff[i * 128 + c] = (e0 * h0 + e1 * h1) / (e0 + e1);
  }
}

// ---------------- K0b: pack weights into MFMA B-fragment bf16 layout --------
// frag f: lane holds B[k = kt*32 + (lane>>4)*8 + j][n = nt*16 + (lane&15)]
__global__ __launch_bounds__(256) void k_pack(
    const float* __restrict__ fc1_w, const float* __restrict__ weff,
    const float* __restrict__ gru_wi, const float* __restrict__ gru_wh,
    unsigned short* __restrict__ wp) {
  int f = blockIdx.x * 256 + threadIdx.x;
  if (f >= FRAGS_TOTAL) return;
  float v[8];
  if (f < FB_WE) {                       // fc1_w [256x128], B[k][n]=w[k*128+n]
    int g = f, kt = g >> 9, nt = (g >> 6) & 7, lane = g & 63;
    int k0 = kt * 32 + ((lane >> 4) << 3), n = nt * 16 + (lane & 15);
#pragma unroll
    for (int j = 0; j < 8; ++j) v[j] = fc1_w[(k0 + j) * H_DIM + n];
  } else if (f < FB_WI) {                // weff [128x128]
    int g = f - FB_WE, kt = g >> 9, nt = (g >> 6) & 7, lane = g & 63;
    int k0 = kt * 32 + ((lane >> 4) << 3), n = nt * 16 + (lane & 15);
#pragma unroll
    for (int j = 0; j < 8; ++j) v[j] = weff[(k0 + j) * H_DIM + n];
  } else if (f < FB_WH) {                // gru_wi [384x128], B[k][g]=wi[g*128+k]
    int g = f - FB_WI, kt = g / 1536, rem = g % 1536, nt = rem >> 6, lane = rem & 63;
    int k0 = kt * 32 + ((lane >> 4) << 3), n = nt * 16 + (lane & 15);
#pragma unroll
    for (int j = 0; j < 8; ++j) v[j] = gru_wi[n * H_DIM + k0 + j];
  } else {                               // gru_wh
    int g = f - FB_WH, kt = g / 1536, rem = g % 1536, nt = rem >> 6, lane = rem & 63;
    int k0 = kt * 32 + ((lane >> 4) << 3), n = nt * 16 + (lane & 15);
#pragma unroll
    for (int j = 0; j < 8; ++j) v[j] = gru_wh[n * H_DIM + k0 + j];
  }
  short8 pk;
#pragma unroll
  for (int j = 0; j < 8; ++j) pk[j] = (short)f2bf(v[j]);
  *(short8*)(wp + (size_t)f * 8) = pk;
}

// ---------------- K1: fused fc1 -> emb -> GRU via MFMA bf16 -----------------
__global__ __launch_bounds__(256) void k_rnn(
    const float* __restrict__ inp, const float* __restrict__ hprev,
    const float* __restrict__ fc1_b, const unsigned short* __restrict__ wp,
    const float* __restrict__ gru_bi, const float* __restrict__ gru_bh,
    float* __restrict__ h_out) {
  __shared__ __align__(16) unsigned short lds_in[8][64][8];   // In A-frags
  __shared__ __align__(16) unsigned short lds_x1[4][64][8];   // X1 A-frags
  __shared__ __align__(16) unsigned short lds_x2[4][64][8];   // X2 A-frags
  __shared__ __align__(16) unsigned short lds_h[4][64][8];    // hprev A-frags
  int t = threadIdx.x;
  int b0 = blockIdx.x * 16;
  int lane = t & 63, w = t >> 6;

  // ---- stage In[16x256] -> bf16 A-frag LDS (coalesced global reads)
#pragma unroll
  for (int i = 0; i < 2; ++i) {
    int idx = i * 256 + t;
    int oct = idx & 31, m = idx >> 5;
    const float* p = inp + (size_t)(b0 + m) * E_DIM + oct * 8;
    floatx4 v0 = *(const floatx4*)p;
    floatx4 v1 = *(const floatx4*)(p + 4);
    short8 pk;
    pk[0] = (short)f2bf(v0.x); pk[1] = (short)f2bf(v0.y);
    pk[2] = (short)f2bf(v0.z); pk[3] = (short)f2bf(v0.w);
    pk[4] = (short)f2bf(v1.x); pk[5] = (short)f2bf(v1.y);
    pk[6] = (short)f2bf(v1.z); pk[7] = (short)f2bf(v1.w);
    *(short8*)&lds_in[oct >> 2][(oct & 3) * 16 + m][0] = pk;
  }
  // ---- stage hprev[16x128] -> bf16 A-frag LDS
  {
    int oct = t & 15, m = t >> 4;
    const float* p = hprev + (size_t)(b0 + m) * H_DIM + oct * 8;
    floatx4 v0 = *(const floatx4*)p;
    floatx4 v1 = *(const floatx4*)(p + 4);
    short8 pk;
    pk[0] = (short)f2bf(v0.x); pk[1] = (short)f2bf(v0.y);
    pk[2] = (short)f2bf(v0.z); pk[3] = (short)f2bf(v0.w);
    pk[4] = (short)f2bf(v1.x); pk[5] = (short)f2bf(v1.y);
    pk[6] = (short)f2bf(v1.z); pk[7] = (short)f2bf(v1.w);
    *(short8*)&lds_h[oct >> 2][(oct & 3) * 16 + m][0] = pk;
  }
  __syncthreads();

  int nt0 = w * 2;
  // ---- fc1: X1 = relu(In @ W1 + b), wave handles n-tiles {nt0, nt0+1}
  {
    short8 aIn[8];
#pragma unroll
    for (int kt = 0; kt < 8; ++kt)
      aIn[kt] = *(const short8*)&lds_in[kt][lane][0];
    floatx4 c1[2] = {{0.f,0.f,0.f,0.f},{0.f,0.f,0.f,0.f}};
#pragma unroll
    for (int kt = 0; kt < 8; ++kt) {
#pragma unroll
      for (int n = 0; n < 2; ++n) {
        short8 b = *(const short8*)(wp +
            ((size_t)(FB_W1 + (kt * 8 + nt0 + n) * 64 + lane)) * 8);
        c1[n] = __builtin_amdgcn_mfma_f32_16x16x32_bf16(aIn[kt], b, c1[n], 0, 0, 0);
      }
    }
#pragma unroll
    for (int n = 0; n < 2; ++n) {
      int col = (nt0 + n) * 16 + (lane & 15);
      float bias = fc1_b[col];
#pragma unroll
      for (int reg = 0; reg < 4; ++reg) {
        float v = fmaxf(c1[n][reg] + bias, 0.f);
        int mm = (lane >> 4) * 4 + reg;
        lds_x1[col >> 5][((col >> 3) & 3) * 16 + mm][col & 7] = f2bf(v);
      }
    }
  }
  __syncthreads();

  // ---- emb: X2 = relu(X1 @ Weff)   (hyp_b2 + softmax already folded)
  {
    short8 a2[4];
#pragma unroll
    for (int kt = 0; kt < 4; ++kt)
      a2[kt] = *(const short8*)&lds_x1[kt][lane][0];
    floatx4 c2[2] = {{0.f,0.f,0.f,0.f},{0.f,0.f,0.f,0.f}};
#pragma unroll
    for (int kt = 0; kt < 4; ++kt) {
#pragma unroll
      for (int n = 0; n < 2; ++n) {
        short8 b = *(const short8*)(wp +
            ((size_t)(FB_WE + (kt * 8 + nt0 + n) * 64 + lane)) * 8);
        c2[n] = __builtin_amdgcn_mfma_f32_16x16x32_bf16(a2[kt], b, c2[n], 0, 0, 0);
      }
    }
#pragma unroll
    for (int n = 0; n < 2; ++n) {
      int col = (nt0 + n) * 16 + (lane & 15);
#pragma unroll
      for (int reg = 0; reg < 4; ++reg) {
        float v = fmaxf(c2[n][reg], 0.f);
        int mm = (lane >> 4) * 4 + reg;
        lds_x2[col >> 5][((col >> 3) & 3) * 16 + mm][col & 7] = f2bf(v);
      }
    }
  }
  __syncthreads();

  // ---- GRU: wave handles column tiles {w, w+4}; r/z/n fused in registers
  {
    short8 ax[4], ah[4];
#pragma unroll
    for (int kt = 0; kt < 4; ++kt) {
      ax[kt] = *(const short8*)&lds_x2[kt][lane][0];
      ah[kt] = *(const short8*)&lds_h[kt][lane][0];
    }
#pragma unroll
    for (int cti = 0; cti < 2; ++cti) {
      int ct = w + cti * 4;
      floatx4 giR = {0.f,0.f,0.f,0.f}, giZ = {0.f,0.f,0.f,0.f}, giN = {0.f,0.f,0.f,0.f};
      floatx4 ghR = {0.f,0.f,0.f,0.f}, ghZ = {0.f,0.f,0.f,0.f}, ghN = {0.f,0.f,0.f,0.f};
#pragma unroll
      for (int kt = 0; kt < 4; ++kt) {
        short8 bR = *(const short8*)(wp + ((size_t)(FB_WI + (kt * 24 + ct) * 64 + lane)) * 8);
        short8 bZ = *(const short8*)(wp + ((size_t)(FB_WI + (kt * 24 + ct + 8) * 64 + lane)) * 8);
        short8 bN = *(const short8*)(wp + ((size_t)(FB_WI + (kt * 24 + ct + 16) * 64 + lane)) * 8);
        short8 cR = *(const short8*)(wp + ((size_t)(FB_WH + (kt * 24 + ct) * 64 + lane)) * 8);
        short8 cZ = *(const short8*)(wp + ((size_t)(FB_WH + (kt * 24 + ct + 8) * 64 + lane)) * 8);
        short8 cN = *(const short8*)(wp + ((size_t)(FB_WH + (kt * 24 + ct + 16) * 64 + lane)) * 8);
        giR = __builtin_amdgcn_mfma_f32_16x16x32_bf16(ax[kt], bR, giR, 0, 0, 0);
        giZ = __builtin_amdgcn_mfma_f32_16x16x32_bf16(ax[kt], bZ, giZ, 0, 0, 0);
        giN = __builtin_amdgcn_mfma_f32_16x16x32_bf16(ax[kt], bN, giN, 0, 0, 0);
        ghR = __builtin_amdgcn_mfma_f32_16x16x32_bf16(ah[kt], cR, ghR, 0, 0, 0);
        ghZ = __builtin_amdgcn_mfma_f32_16x16x32_bf16(ah[kt], cZ, ghZ, 0, 0, 0);
        ghN = __builtin_amdgcn_mfma_f32_16x16x32_bf16(ah[kt], cN, ghN, 0, 0, 0);
      }
      int c = ct * 16 + (lane & 15);
      float bir = gru_bi[c], biz = gru_bi[128 + c], bin = gru_bi[256 + c];
      float bhr = gru_bh[c], bhz = gru_bh[128 + c], bhn = gru_bh[256 + c];
#pragma unroll
      for (int reg = 0; reg < 4; ++reg) {
        int row = b0 + (lane >> 4) * 4 + reg;
        float r = 1.f / (1.f + expf(-(giR[reg] + bir + ghR[reg] + bhr)));
        float z = 1.f / (1.f + expf(-(giZ[reg] + biz + ghZ[reg] + bhz)));
        float n = tanhf(giN[reg] + bin + r * (ghN[reg] + bhn));
        float hp = hprev[(size_t)row * H_DIM + c];
        h_out[(size_t)row * H_DIM + c] = (1.f - z) * n + z * hp;
      }
    }
  }
}

// ---------------- K2: quantile embedding q_phi = relu(cos @ phi_w + b) ------
__global__ __launch_bounds__(128) void k_qphi(
    const float* __restrict__ rnd, const float* __restrict__ phi_w,
    const float* __restrict__ phi_b, float* __restrict__ qphi,
    float* __restrict__ rq_out) {
  const int R = 8;
  __shared__ float cos_s[R][QEDv];
  int t = threadIdx.x;
  int r0 = blockIdx.x * R;
#pragma unroll
  for (int ii = 0; ii < R * QEDv / 128; ++ii) {
    int idx = t + ii * 128;
    int r = idx >> 6, f = idx & 63;
    cos_s[r][f] = cosf(3.14159265358979323846f * (float)f * rnd[r0 + r]);
  }
  if (t < R) rq_out[r0 + t] = rnd[r0 + t];
  __syncthreads();
  float acc[R];
  float bv = phi_b[t];
#pragma unroll
  for (int r = 0; r < R; ++r) acc[r] = bv;
#pragma unroll 4
  for (int f = 0; f < QEDv; ++f) {
    float wv = phi_w[f * H_DIM + t];
#pragma unroll
    for (int r = 0; r < R; ++r) acc[r] = fmaf(cos_s[r][f], wv, acc[r]);
  }
#pragma unroll
  for (int r = 0; r < R; ++r)
    qphi[(size_t)(r0 + r) * H_DIM + t] = fmaxf(acc[r], 0.f);
}

// ---------------- K3: q = (h (x) q_phi) @ fc2_w + b, sort over quantiles ----
__global__ __launch_bounds__(256) void k_qsort(
    const float* __restrict__ h_in, const float* __restrict__ qphi,
    const float* __restrict__ fc2_w, const float* __restrict__ fc2_b,
    float* __restrict__ q_out) {
  const int BB = 16;
  __shared__ float h_s[BB][H_DIM + 4];
  __shared__ float qp_s[BB][H_DIM + 4];
  __shared__ float w_s[NAv][H_DIM + 1];
  __shared__ float b_s[NAv];
  int t = threadIdx.x;
  int b0 = blockIdx.x * BB;
  {
    const float4* hs = (const float4*)(h_in + (size_t)b0 * H_DIM);
    for (int idx = t; idx < BB * H_DIM / 4; idx += 256) {
      int row = idx >> 5, col = idx & 31;
      ((float4*)&h_s[row][0])[col] = hs[idx];
    }
    const float4* qs = (const float4*)(qphi + (size_t)(b0 / NAGv) * NQv * H_DIM);
    for (int idx = t; idx < BB * H_DIM / 4; idx += 256) {
      int row = idx >> 5, col = idx & 31;
      ((float4*)&qp_s[row][0])[col] = qs[idx];
    }
    for (int idx = t; idx < H_DIM * NAv; idx += 256) {
      int cc = idx / NAv, aa = idx - cc * NAv;
      w_s[aa][cc] = fc2_w[idx];
    }
    if (t < NAv) b_s[t] = fc2_b[t];
  }
  __syncthreads();
  if (t >= BB * NAv) return;
  int bl = t / NAv, a = t - bl * NAv;
  int glb = (bl >> 3) << 3;
  float qv[NQv];
  float bias = b_s[a];
#pragma unroll
  for (int k = 0; k < NQv; ++k) qv[k] = bias;
  for (int cc = 0; cc < H_DIM; ++cc) {
    float hw = h_s[bl][cc] * w_s[a][cc];
#pragma unroll
    for (int k = 0; k < NQv; ++k)
      qv[k] = fmaf(hw, qp_s[glb + k][cc], qv[k]);
  }
#define CE(i, j) { float lo_ = fminf(qv[i], qv[j]); float hi_ = fmaxf(qv[i], qv[j]); qv[i] = lo_; qv[j] = hi_; }
  CE(0,1) CE(2,3) CE(4,5) CE(6,7)
  CE(0,2) CE(1,3) CE(4,6) CE(5,7)
  CE(1,2) CE(5,6)
  CE(0,4) CE(1,5) CE(2,6) CE(3,7)
  CE(2,4) CE(3,5)
  CE(1,2) CE(3,4) CE(5,6)
#undef CE
  float4* o4 = (float4*)(q_out + (size_t)((b0 + bl) * NAv + a) * NQv);
  o4[0] = make_float4(qv[0], qv[1], qv[2], qv[3]);
  o4[1] = make_float4(qv[4], qv[5], qv[6], qv[7]);
}

extern "C" void kernel_launch(void* const* d_in, const int* in_sizes, int n_in,
                              void* d_out, int out_size, void* d_ws, size_t ws_size,
                              hipStream_t stream) {
  (void)in_sizes; (void)n_in; (void)out_size; (void)ws_size;
  const float* inp      = (const float*)d_in[0];
  const float* hidden   = (const float*)d_in[1];
  const float* rnd      = (const float*)d_in[2];
  const float* fc1_w    = (const float*)d_in[3];
  const float* fc1_b    = (const float*)d_in[4];
  const float* hyp_w1   = (const float*)d_in[5];
  const float* hyp_b1   = (const float*)d_in[6];
  const float* hyp_w2   = (const float*)d_in[7];
  const float* hyp_b2   = (const float*)d_in[8];
  const float* merger_w = (const float*)d_in[9];
  const float* gru_wi   = (const float*)d_in[10];
  const float* gru_wh   = (const float*)d_in[11];
  const float* gru_bi   = (const float*)d_in[12];
  const float* gru_bh   = (const float*)d_in[13];
  const float* phi_w    = (const float*)d_in[14];
  const float* phi_b    = (const float*)d_in[15];
  const float* fc2_w    = (const float*)d_in[16];
  const float* fc2_b    = (const float*)d_in[17];
  float* out  = (float*)d_out;
  float* ws   = (float*)d_ws;
  float* weff = ws + WS_WEFF;
  float* qphi = ws + WS_QPHI;
  unsigned short* wp = (unsigned short*)(ws + WS_PACK);
  float* h_out = out + OUT_H_OFF;

  k_weff<<<dim3(256), dim3(256), 0, stream>>>(hyp_w1, hyp_b1, hyp_w2, hyp_b2,
                                              merger_w, weff);
  k_pack<<<dim3(72), dim3(256), 0, stream>>>(fc1_w, weff, gru_wi, gru_wh, wp);
  k_qphi<<<dim3(512), dim3(128), 0, stream>>>(rnd, phi_w, phi_b, qphi,
                                              out + OUT_RQ_OFF);
  k_rnn<<<dim3(256), dim3(256), 0, stream>>>(inp, hidden, fc1_b, wp,
                                             gru_bi, gru_bh, h_out);
  k_qsort<<<dim3(256), dim3(256), 0, stream>>>(h_out, qphi, fc2_w, fc2_b, out);
}

// Round 3
// 109.420 us; speedup vs baseline: 1.6205x; 1.1535x over previous
//
#include <hip/hip_runtime.h>
#include <math.h>

typedef __attribute__((ext_vector_type(8))) short short8;
typedef __attribute__((ext_vector_type(4))) float floatx4;

#define E_DIM 256
#define H_DIM 128
#define NQv 8
#define QEDv 64
#define HYPv 64
#define NAv 14
#define NAGv 8
#define W2COL 32768   // H*H*HEADS

#define OUT_H_OFF 458752
#define OUT_RQ_OFF 983040

// packed frag units (unit = one lane-slot of 8 bf16; frag = 64 units)
#define FB_W1  0                // fc1:  8kt x 8nt  -> 4096 units
#define FB_WE  4096             // weff: 4kt x 8nt  -> 2048 units (written by k_weff)
#define FB_WI  6144             // gru_wi^T: 4kt x 24nt -> 6144 units
#define FB_WH  12288            // gru_wh^T: 4kt x 24nt -> 6144 units
#define FB_PHI 18432            // phi_w: 2kt x 8nt -> 1024 units
#define FB_FC2 19456            // fc2_w (N pad 16): 4kt x 1nt -> 256 units
#define PACK_UNITS 17664        // k_pack covers all but FB_WE

// shared-memory layout for k_main (bytes)
#define SM_IN   0               // ushort [8][64][8]  = 8192   (A-frags of In)
#define SM_X1   8192            // ushort [4][64][8]  = 4096
#define SM_X2   12288           // ushort [4][64][8]  = 4096
#define SM_H    16384           // ushort [4][64][8]  = 4096
#define SM_PART 0               // float  [4][8][64][4] = 32768 (overlays IN/X1/X2/H)
#define SM_HF   32768           // float  [16][132]   = 8448
#define SM_QP   41216           // ushort [16][136]   = 4352
#define SM_TOTAL 45568

__device__ __forceinline__ unsigned short f2bf(float x) {
  unsigned u = __builtin_bit_cast(unsigned, x);
  u += 0x7FFFu + ((u >> 16) & 1u);
  return (unsigned short)(u >> 16);
}
__device__ __forceinline__ float bf2f(unsigned short s) {
  return __builtin_bit_cast(float, ((unsigned)s) << 16);
}

// ---------------- K0: W_eff -> packed bf16 B-frags (FB_WE) ------------------
// prev == ones => hypernet output is sample-independent; merger softmax folded.
__global__ __launch_bounds__(256) void k_weff(
    const float* __restrict__ hyp_w1, const float* __restrict__ hyp_b1,
    const float* __restrict__ hyp_w2, const float* __restrict__ hyp_b2,
    const float* __restrict__ merger_w, unsigned short* __restrict__ wp) {
  __shared__ float hh[HYPv];
  __shared__ float part[4][2][64];
  int t = threadIdx.x;
  if (t < HYPv) {
    float s = hyp_b1[t];
#pragma unroll
    for (int i = 0; i < NQv; ++i) s += hyp_w1[i * HYPv + t];
    hh[t] = fmaxf(s, 0.f);
  }
  __syncthreads();
  int w = t >> 6, lane = t & 63;
  int i = blockIdx.x >> 1;               // weff row (= GEMM k index)
  int cbase = (blockIdx.x & 1) * 64;
  int o0 = i * 256 + cbase + lane;
  float a0 = 0.f, a1 = 0.f;
#pragma unroll
  for (int jj = 0; jj < 16; ++jj) {
    int j = w * 16 + jj;
    float hj = hh[j];
    a0 = fmaf(hj, hyp_w2[j * W2COL + o0], a0);
    a1 = fmaf(hj, hyp_w2[j * W2COL + o0 + 128], a1);
  }
  part[w][0][lane] = a0;
  part[w][1][lane] = a1;
  __syncthreads();
  if (t < 64) {
    int c = cbase + t;                   // weff col (= GEMM n index)
    float h0 = part[0][0][t] + part[1][0][t] + part[2][0][t] + part[3][0][t]
               + hyp_b2[i * 256 + c];
    float h1 = part[0][1][t] + part[1][1][t] + part[2][1][t] + part[3][1][t]
               + hyp_b2[i * 256 + c + 128];
    float m0 = merger_w[c], m1 = merger_w[128 + c];
    float mx = fmaxf(m0, m1);
    float e0 = expf(m0 - mx), e1 = expf(m1 - mx);
    float val = (e0 * h0 + e1 * h1) / (e0 + e1);
    int unit = FB_WE + ((i >> 5) * 8 + (c >> 4)) * 64 + ((i >> 3) & 3) * 16 + (c & 15);
    wp[(size_t)unit * 8 + (i & 7)] = f2bf(val);
  }
}

// ---------------- K0b: pack static weights into MFMA B-frag bf16 -----------
__global__ __launch_bounds__(256) void k_pack(
    const float* __restrict__ fc1_w, const float* __restrict__ gru_wi,
    const float* __restrict__ gru_wh, const float* __restrict__ phi_w,
    const float* __restrict__ fc2_w, unsigned short* __restrict__ wp) {
  int u = blockIdx.x * 256 + threadIdx.x;
  if (u >= PACK_UNITS) return;
  float v[8];
  int f;
  if (u < 4096) {                        // fc1_w [256x128], B[k][n]=w[k*128+n]
    int g = u, nt = (g >> 6) & 7, lane = g & 63;
    int k0 = (g >> 9) * 32 + ((lane >> 4) << 3), n = nt * 16 + (lane & 15);
    f = FB_W1 + g;
#pragma unroll
    for (int j = 0; j < 8; ++j) v[j] = fc1_w[(k0 + j) * H_DIM + n];
  } else if (u < 10240) {                // gru_wi [384x128], B[k][g]=wi[g*128+k]
    int g = u - 4096, kt = g / 1536, rem = g % 1536, nt = rem >> 6, lane = rem & 63;
    int k0 = kt * 32 + ((lane >> 4) << 3), n = nt * 16 + (lane & 15);
    f = FB_WI + g;
#pragma unroll
    for (int j = 0; j < 8; ++j) v[j] = gru_wi[n * H_DIM + k0 + j];
  } else if (u < 16384) {                // gru_wh
    int g = u - 10240, kt = g / 1536, rem = g % 1536, nt = rem >> 6, lane = rem & 63;
    int k0 = kt * 32 + ((lane >> 4) << 3), n = nt * 16 + (lane & 15);
    f = FB_WH + g;
#pragma unroll
    for (int j = 0; j < 8; ++j) v[j] = gru_wh[n * H_DIM + k0 + j];
  } else if (u < 17408) {                // phi_w [64x128], B[k][n]=w[k*128+n]
    int g = u - 16384, kt = g >> 9, nt = (g >> 6) & 7, lane = g & 63;
    int k0 = kt * 32 + ((lane >> 4) << 3), n = nt * 16 + (lane & 15);
    f = FB_PHI + g;
#pragma unroll
    for (int j = 0; j < 8; ++j) v[j] = phi_w[(k0 + j) * H_DIM + n];
  } else {                               // fc2_w [128x14], pad N to 16
    int g = u - 17408, kt = g >> 6, lane = g & 63;
    int k0 = kt * 32 + ((lane >> 4) << 3), n = lane & 15;
    f = FB_FC2 + g;
#pragma unroll
    for (int j = 0; j < 8; ++j) v[j] = (n < NAv) ? fc2_w[(k0 + j) * NAv + n] : 0.f;
  }
  short8 pk;
#pragma unroll
  for (int j = 0; j < 8; ++j) pk[j] = (short)f2bf(v[j]);
  *(short8*)(wp + (size_t)f * 8) = pk;
}

// ---------------- K1: fused qphi + fc1 -> emb -> GRU -> fc2 -> sort ---------
__global__ __launch_bounds__(256) void k_main(
    const float* __restrict__ inp, const float* __restrict__ hprev,
    const float* __restrict__ rnd, const float* __restrict__ fc1_b,
    const unsigned short* __restrict__ wp,
    const float* __restrict__ gru_bi, const float* __restrict__ gru_bh,
    const float* __restrict__ phi_b, const float* __restrict__ fc2_b,
    float* __restrict__ h_out, float* __restrict__ q_out,
    float* __restrict__ rq_out) {
  __shared__ __align__(16) char smem[SM_TOTAL];
  unsigned short (*lds_in)[64][8] = (unsigned short(*)[64][8])(smem + SM_IN);
  unsigned short (*lds_x1)[64][8] = (unsigned short(*)[64][8])(smem + SM_X1);
  unsigned short (*lds_x2)[64][8] = (unsigned short(*)[64][8])(smem + SM_X2);
  unsigned short (*lds_h)[64][8]  = (unsigned short(*)[64][8])(smem + SM_H);
  float (*lds_hf)[132]            = (float(*)[132])(smem + SM_HF);
  unsigned short (*lds_qp)[136]   = (unsigned short(*)[136])(smem + SM_QP);
  float* lds_part                 = (float*)(smem + SM_PART);

  int t = threadIdx.x;
  int b0 = blockIdx.x * 16;
  int lane = t & 63, w = t >> 6;
  int quad = lane >> 4, l16 = lane & 15;

  if (t < 16) rq_out[b0 + t] = rnd[b0 + t];

  // ---- stage In[16x256] -> bf16 A-frag LDS
#pragma unroll
  for (int i = 0; i < 2; ++i) {
    int idx = i * 256 + t;
    int oct = idx & 31, m = idx >> 5;
    const float* p = inp + (size_t)(b0 + m) * E_DIM + oct * 8;
    floatx4 v0 = *(const floatx4*)p;
    floatx4 v1 = *(const floatx4*)(p + 4);
    short8 pk;
    pk[0] = (short)f2bf(v0.x); pk[1] = (short)f2bf(v0.y);
    pk[2] = (short)f2bf(v0.z); pk[3] = (short)f2bf(v0.w);
    pk[4] = (short)f2bf(v1.x); pk[5] = (short)f2bf(v1.y);
    pk[6] = (short)f2bf(v1.z); pk[7] = (short)f2bf(v1.w);
    *(short8*)&lds_in[oct >> 2][(oct & 3) * 16 + m][0] = pk;
  }
  // ---- stage hprev[16x128] -> bf16 A-frag LDS
  {
    int oct = t & 15, m = t >> 4;
    const float* p = hprev + (size_t)(b0 + m) * H_DIM + oct * 8;
    floatx4 v0 = *(const floatx4*)p;
    floatx4 v1 = *(const floatx4*)(p + 4);
    short8 pk;
    pk[0] = (short)f2bf(v0.x); pk[1] = (short)f2bf(v0.y);
    pk[2] = (short)f2bf(v0.z); pk[3] = (short)f2bf(v0.w);
    pk[4] = (short)f2bf(v1.x); pk[5] = (short)f2bf(v1.y);
    pk[6] = (short)f2bf(v1.z); pk[7] = (short)f2bf(v1.w);
    *(short8*)&lds_h[oct >> 2][(oct & 3) * 16 + m][0] = pk;
  }

  // ---- phi: qp[m_qp][col] = relu(cos(pi*f*rq) @ phi_w + b), MFMA, M=16,K=64
  {
    float rqv = rnd[b0 + l16];           // row m_qp = l16 <-> rnd[blk*16+m_qp]
    short8 aC[2];
#pragma unroll
    for (int kt = 0; kt < 2; ++kt) {
#pragma unroll
      for (int j = 0; j < 8; ++j) {
        float f = (float)(kt * 32 + quad * 8 + j);
        aC[kt][j] = (short)f2bf(__cosf(3.14159265358979f * f * rqv));
      }
    }
    floatx4 cP[2] = {{0.f,0.f,0.f,0.f},{0.f,0.f,0.f,0.f}};
#pragma unroll
    for (int kt = 0; kt < 2; ++kt) {
#pragma unroll
      for (int ni = 0; ni < 2; ++ni) {
        int nt = w * 2 + ni;
        short8 b = *(const short8*)(wp + ((size_t)(FB_PHI + (kt * 8 + nt) * 64 + lane)) * 8);
        cP[ni] = __builtin_amdgcn_mfma_f32_16x16x32_bf16(aC[kt], b, cP[ni], 0, 0, 0);
      }
    }
#pragma unroll
    for (int ni = 0; ni < 2; ++ni) {
      int col = (w * 2 + ni) * 16 + l16;
      float bias = phi_b[col];
#pragma unroll
      for (int reg = 0; reg < 4; ++reg) {
        int m_qp = quad * 4 + reg;
        lds_qp[m_qp][col] = f2bf(fmaxf(cP[ni][reg] + bias, 0.f));
      }
    }
  }
  __syncthreads();

  int nt0 = w * 2;
  // ---- fc1: X1 = relu(In @ W1 + b)
  {
    short8 aIn[8];
#pragma unroll
    for (int kt = 0; kt < 8; ++kt)
      aIn[kt] = *(const short8*)&lds_in[kt][lane][0];
    floatx4 c1[2] = {{0.f,0.f,0.f,0.f},{0.f,0.f,0.f,0.f}};
#pragma unroll
    for (int kt = 0; kt < 8; ++kt) {
#pragma unroll
      for (int n = 0; n < 2; ++n) {
        short8 b = *(const short8*)(wp + ((size_t)(FB_W1 + (kt * 8 + nt0 + n) * 64 + lane)) * 8);
        c1[n] = __builtin_amdgcn_mfma_f32_16x16x32_bf16(aIn[kt], b, c1[n], 0, 0, 0);
      }
    }
#pragma unroll
    for (int n = 0; n < 2; ++n) {
      int col = (nt0 + n) * 16 + l16;
      float bias = fc1_b[col];
#pragma unroll
      for (int reg = 0; reg < 4; ++reg) {
        float v = fmaxf(c1[n][reg] + bias, 0.f);
        lds_x1[col >> 5][((col >> 3) & 3) * 16 + quad * 4 + reg][col & 7] = f2bf(v);
      }
    }
  }
  __syncthreads();

  // ---- emb: X2 = relu(X1 @ Weff)
  {
    short8 a2[4];
#pragma unroll
    for (int kt = 0; kt < 4; ++kt)
      a2[kt] = *(const short8*)&lds_x1[kt][lane][0];
    floatx4 c2[2] = {{0.f,0.f,0.f,0.f},{0.f,0.f,0.f,0.f}};
#pragma unroll
    for (int kt = 0; kt < 4; ++kt) {
#pragma unroll
      for (int n = 0; n < 2; ++n) {
        short8 b = *(const short8*)(wp + ((size_t)(FB_WE + (kt * 8 + nt0 + n) * 64 + lane)) * 8);
        c2[n] = __builtin_amdgcn_mfma_f32_16x16x32_bf16(a2[kt], b, c2[n], 0, 0, 0);
      }
    }
#pragma unroll
    for (int n = 0; n < 2; ++n) {
      int col = (nt0 + n) * 16 + l16;
#pragma unroll
      for (int reg = 0; reg < 4; ++reg) {
        float v = fmaxf(c2[n][reg], 0.f);
        lds_x2[col >> 5][((col >> 3) & 3) * 16 + quad * 4 + reg][col & 7] = f2bf(v);
      }
    }
  }
  __syncthreads();

  // ---- GRU: column tiles {w, w+4}; writes h_out (global) + lds_hf (f32)
  {
    short8 ax[4], ah[4];
#pragma unroll
    for (int kt = 0; kt < 4; ++kt) {
      ax[kt] = *(const short8*)&lds_x2[kt][lane][0];
      ah[kt] = *(const short8*)&lds_h[kt][lane][0];
    }
#pragma unroll
    for (int cti = 0; cti < 2; ++cti) {
      int ct = w + cti * 4;
      floatx4 giR = {0.f,0.f,0.f,0.f}, giZ = {0.f,0.f,0.f,0.f}, giN = {0.f,0.f,0.f,0.f};
      floatx4 ghR = {0.f,0.f,0.f,0.f}, ghZ = {0.f,0.f,0.f,0.f}, ghN = {0.f,0.f,0.f,0.f};
#pragma unroll
      for (int kt = 0; kt < 4; ++kt) {
        short8 bR = *(const short8*)(wp + ((size_t)(FB_WI + (kt * 24 + ct) * 64 + lane)) * 8);
        short8 bZ = *(const short8*)(wp + ((size_t)(FB_WI + (kt * 24 + ct + 8) * 64 + lane)) * 8);
        short8 bN = *(const short8*)(wp + ((size_t)(FB_WI + (kt * 24 + ct + 16) * 64 + lane)) * 8);
        short8 cR = *(const short8*)(wp + ((size_t)(FB_WH + (kt * 24 + ct) * 64 + lane)) * 8);
        short8 cZ = *(const short8*)(wp + ((size_t)(FB_WH + (kt * 24 + ct + 8) * 64 + lane)) * 8);
        short8 cN = *(const short8*)(wp + ((size_t)(FB_WH + (kt * 24 + ct + 16) * 64 + lane)) * 8);
        giR = __builtin_amdgcn_mfma_f32_16x16x32_bf16(ax[kt], bR, giR, 0, 0, 0);
        giZ = __builtin_amdgcn_mfma_f32_16x16x32_bf16(ax[kt], bZ, giZ, 0, 0, 0);
        giN = __builtin_amdgcn_mfma_f32_16x16x32_bf16(ax[kt], bN, giN, 0, 0, 0);
        ghR = __builtin_amdgcn_mfma_f32_16x16x32_bf16(ah[kt], cR, ghR, 0, 0, 0);
        ghZ = __builtin_amdgcn_mfma_f32_16x16x32_bf16(ah[kt], cZ, ghZ, 0, 0, 0);
        ghN = __builtin_amdgcn_mfma_f32_16x16x32_bf16(ah[kt], cN, ghN, 0, 0, 0);
      }
      int c = ct * 16 + l16;
      float bir = gru_bi[c], biz = gru_bi[128 + c], bin = gru_bi[256 + c];
      float bhr = gru_bh[c], bhz = gru_bh[128 + c], bhn = gru_bh[256 + c];
#pragma unroll
      for (int reg = 0; reg < 4; ++reg) {
        int rl = quad * 4 + reg;
        int row = b0 + rl;
        float r = 1.f / (1.f + expf(-(giR[reg] + bir + ghR[reg] + bhr)));
        float z = 1.f / (1.f + expf(-(giZ[reg] + biz + ghZ[reg] + bhz)));
        float n = tanhf(giN[reg] + bin + r * (ghN[reg] + bhn));
        float hp = hprev[(size_t)row * H_DIM + c];
        float hv = (1.f - z) * n + z * hp;
        h_out[(size_t)row * H_DIM + c] = hv;
        lds_hf[rl][c] = hv;
      }
    }
  }
  __syncthreads();

  // ---- fc2 via MFMA, K split across waves (wave w owns k-slice w*32..+31)
  {
    int m = l16;                         // sample (A row)
    int k0 = w * 32 + quad * 8;
    const float* hptr = &lds_hf[m][k0];
    floatx4 h0 = *(const floatx4*)hptr;
    floatx4 h1 = *(const floatx4*)(hptr + 4);
    float hf[8] = {h0.x, h0.y, h0.z, h0.w, h1.x, h1.y, h1.z, h1.w};
    short8 bF = *(const short8*)(wp + ((size_t)(FB_FC2 + w * 64 + lane)) * 8);
    int qbase = (m >> 3) * 8;
    floatx4 cQ[8];
#pragma unroll
    for (int q = 0; q < NQv; ++q) cQ[q] = (floatx4){0.f,0.f,0.f,0.f};
#pragma unroll
    for (int q = 0; q < NQv; ++q) {
      short8 qpv = *(const short8*)&lds_qp[qbase + q][k0];
      short8 au;
#pragma unroll
      for (int j = 0; j < 8; ++j)
        au[j] = (short)f2bf(hf[j] * bf2f((unsigned short)qpv[j]));
      cQ[q] = __builtin_amdgcn_mfma_f32_16x16x32_bf16(au, bF, cQ[q], 0, 0, 0);
    }
#pragma unroll
    for (int q = 0; q < NQv; ++q)
      *(floatx4*)&lds_part[((w * 8 + q) * 64 + lane) * 4] = cQ[q];
  }
  __syncthreads();

  // ---- cross-wave K-reduce + bias + sort + store
  {
    int s = t >> 4, a = t & 15;
    int pl = (s >> 2) * 16 + a;          // C-layout lane for row s
    int pr = s & 3;                      // C-layout reg for row s
    float bias = (a < NAv) ? fc2_b[a] : 0.f;
    float qv[NQv];
#pragma unroll
    for (int q = 0; q < NQv; ++q) {
      float acc = bias;
#pragma unroll
      for (int ww = 0; ww < 4; ++ww)
        acc += lds_part[((ww * 8 + q) * 64 + pl) * 4 + pr];
      qv[q] = acc;
    }
#define CE(i, j) { float lo_ = fminf(qv[i], qv[j]); float hi_ = fmaxf(qv[i], qv[j]); qv[i] = lo_; qv[j] = hi_; }
    CE(0,1) CE(2,3) CE(4,5) CE(6,7)
    CE(0,2) CE(1,3) CE(4,6) CE(5,7)
    CE(1,2) CE(5,6)
    CE(0,4) CE(1,5) CE(2,6) CE(3,7)
    CE(2,4) CE(3,5)
    CE(1,2) CE(3,4) CE(5,6)
#undef CE
    if (a < NAv) {
      float4* o4 = (float4*)(q_out + (size_t)((b0 + s) * NAv + a) * NQv);
      o4[0] = make_float4(qv[0], qv[1], qv[2], qv[3]);
      o4[1] = make_float4(qv[4], qv[5], qv[6], qv[7]);
    }
  }
}

extern "C" void kernel_launch(void* const* d_in, const int* in_sizes, int n_in,
                              void* d_out, int out_size, void* d_ws, size_t ws_size,
                              hipStream_t stream) {
  (void)in_sizes; (void)n_in; (void)out_size; (void)ws_size;
  const float* inp      = (const float*)d_in[0];
  const float* hidden   = (const float*)d_in[1];
  const float* rnd      = (const float*)d_in[2];
  const float* fc1_w    = (const float*)d_in[3];
  const float* fc1_b    = (const float*)d_in[4];
  const float* hyp_w1   = (const float*)d_in[5];
  const float* hyp_b1   = (const float*)d_in[6];
  const float* hyp_w2   = (const float*)d_in[7];
  const float* hyp_b2   = (const float*)d_in[8];
  const float* merger_w = (const float*)d_in[9];
  const float* gru_wi   = (const float*)d_in[10];
  const float* gru_wh   = (const float*)d_in[11];
  const float* gru_bi   = (const float*)d_in[12];
  const float* gru_bh   = (const float*)d_in[13];
  const float* phi_w    = (const float*)d_in[14];
  const float* phi_b    = (const float*)d_in[15];
  const float* fc2_w    = (const float*)d_in[16];
  const float* fc2_b    = (const float*)d_in[17];
  float* out  = (float*)d_out;
  unsigned short* wp = (unsigned short*)d_ws;
  float* h_out = out + OUT_H_OFF;

  k_pack<<<dim3(69), dim3(256), 0, stream>>>(fc1_w, gru_wi, gru_wh, phi_w,
                                             fc2_w, wp);
  k_weff<<<dim3(256), dim3(256), 0, stream>>>(hyp_w1, hyp_b1, hyp_w2, hyp_b2,
                                              merger_w, wp);
  k_main<<<dim3(256), dim3(256), 0, stream>>>(inp, hidden, rnd, fc1_b, wp,
                                              gru_bi, gru_bh, phi_b, fc2_b,
                                              h_out, out, out + OUT_RQ_OFF);
}

// Round 4
// 107.153 us; speedup vs baseline: 1.6548x; 1.0212x over previous
//
#include <hip/hip_runtime.h>
#include <math.h>

typedef __attribute__((ext_vector_type(8))) short short8;
typedef __attribute__((ext_vector_type(4))) float floatx4;

#define E_DIM 256
#define H_DIM 128
#define NQv 8
#define QEDv 64
#define HYPv 64
#define NAv 14
#define NAGv 8
#define W2COL 32768   // H*H*HEADS

#define OUT_H_OFF 458752
#define OUT_RQ_OFF 983040

// packed frag units (unit = one lane-slot of 8 bf16; frag = 64 units)
#define FB_W1  0                // fc1:  8kt x 8nt  -> 4096 units
#define FB_WE  4096             // weff: 4kt x 8nt  -> 2048 units (written by weff part)
#define FB_WI  6144             // gru_wi^T: 4kt x 24nt -> 6144 units
#define FB_WH  12288            // gru_wh^T: 4kt x 24nt -> 6144 units
#define FB_PHI 18432            // phi_w: 2kt x 8nt -> 1024 units
#define FB_FC2 19456            // fc2_w (N pad 16): 4kt x 1nt -> 256 units
#define PACK_UNITS 17664        // pack part covers all but FB_WE
#define PACK_BLOCKS 69          // ceil(17664/256)
#define WEFF_BLOCKS 256

// shared-memory layout for k_main (bytes)
#define SM_IN   0               // ushort [8][64][8]  = 8192   (A-frags of In)
#define SM_X1   8192            // ushort [4][64][8]  = 4096
#define SM_X2   12288           // ushort [4][64][8]  = 4096
#define SM_H    16384           // ushort [4][64][8]  = 4096
#define SM_PART 0               // float  [4][8][64][4] = 32768 (overlays IN/X1/X2/H)
#define SM_HF   32768           // float  [16][132]   = 8448
#define SM_QP   41216           // ushort [16][136]   = 4352
#define SM_TOTAL 45568

__device__ __forceinline__ unsigned short f2bf(float x) {
  unsigned u = __builtin_bit_cast(unsigned, x);
  u += 0x7FFFu + ((u >> 16) & 1u);
  return (unsigned short)(u >> 16);
}
__device__ __forceinline__ float bf2f(unsigned short s) {
  return __builtin_bit_cast(float, ((unsigned)s) << 16);
}
__device__ __forceinline__ float fsigmoid(float x) {
  return 1.f / (1.f + __expf(-x));
}
__device__ __forceinline__ float ftanh(float x) {
  float t = __expf(-2.f * x);
  return (1.f - t) / (1.f + t);
}

// ---------------- K0: fused weight prep (pack + hypernet W_eff) -------------
// blocks [0, PACK_BLOCKS): pack static weights into MFMA B-frag bf16.
// blocks [PACK_BLOCKS, PACK_BLOCKS+WEFF_BLOCKS): hypernet -> W_eff B-frags.
// prev == ones => hypernet output is sample-independent; merger softmax folded.
__global__ __launch_bounds__(256) void k_prep(
    const float* __restrict__ fc1_w, const float* __restrict__ gru_wi,
    const float* __restrict__ gru_wh, const float* __restrict__ phi_w,
    const float* __restrict__ fc2_w,
    const float* __restrict__ hyp_w1, const float* __restrict__ hyp_b1,
    const float* __restrict__ hyp_w2, const float* __restrict__ hyp_b2,
    const float* __restrict__ merger_w, unsigned short* __restrict__ wp) {
  __shared__ float hh[HYPv];
  __shared__ float part[4][2][64];
  int t = threadIdx.x;

  if (blockIdx.x < PACK_BLOCKS) {
    // ---------------- pack branch ----------------
    int u = blockIdx.x * 256 + t;
    if (u >= PACK_UNITS) return;
    float v[8];
    int f;
    if (u < 4096) {                      // fc1_w [256x128], B[k][n]=w[k*128+n]
      int g = u, nt = (g >> 6) & 7, lane = g & 63;
      int k0 = (g >> 9) * 32 + ((lane >> 4) << 3), n = nt * 16 + (lane & 15);
      f = FB_W1 + g;
#pragma unroll
      for (int j = 0; j < 8; ++j) v[j] = fc1_w[(k0 + j) * H_DIM + n];
    } else if (u < 10240) {              // gru_wi [384x128], B[k][g]=wi[g*128+k]
      int g = u - 4096, kt = g / 1536, rem = g % 1536, nt = rem >> 6, lane = rem & 63;
      int k0 = kt * 32 + ((lane >> 4) << 3), n = nt * 16 + (lane & 15);
      f = FB_WI + g;
#pragma unroll
      for (int j = 0; j < 8; ++j) v[j] = gru_wi[n * H_DIM + k0 + j];
    } else if (u < 16384) {              // gru_wh
      int g = u - 10240, kt = g / 1536, rem = g % 1536, nt = rem >> 6, lane = rem & 63;
      int k0 = kt * 32 + ((lane >> 4) << 3), n = nt * 16 + (lane & 15);
      f = FB_WH + g;
#pragma unroll
      for (int j = 0; j < 8; ++j) v[j] = gru_wh[n * H_DIM + k0 + j];
    } else if (u < 17408) {              // phi_w [64x128], B[k][n]=w[k*128+n]
      int g = u - 16384, kt = g >> 9, nt = (g >> 6) & 7, lane = g & 63;
      int k0 = kt * 32 + ((lane >> 4) << 3), n = nt * 16 + (lane & 15);
      f = FB_PHI + g;
#pragma unroll
      for (int j = 0; j < 8; ++j) v[j] = phi_w[(k0 + j) * H_DIM + n];
    } else {                             // fc2_w [128x14], pad N to 16
      int g = u - 17408, kt = g >> 6, lane = g & 63;
      int k0 = kt * 32 + ((lane >> 4) << 3), n = lane & 15;
      f = FB_FC2 + g;
#pragma unroll
      for (int j = 0; j < 8; ++j) v[j] = (n < NAv) ? fc2_w[(k0 + j) * NAv + n] : 0.f;
    }
    short8 pk;
#pragma unroll
    for (int j = 0; j < 8; ++j) pk[j] = (short)f2bf(v[j]);
    *(short8*)(wp + (size_t)f * 8) = pk;
    return;
  }

  // ---------------- weff branch ----------------
  int blk = blockIdx.x - PACK_BLOCKS;
  if (t < HYPv) {
    float s = hyp_b1[t];
#pragma unroll
    for (int i = 0; i < NQv; ++i) s += hyp_w1[i * HYPv + t];
    hh[t] = fmaxf(s, 0.f);
  }
  __syncthreads();
  int w = t >> 6, lane = t & 63;
  int i = blk >> 1;                      // weff row (= GEMM k index)
  int cbase = (blk & 1) * 64;
  int o0 = i * 256 + cbase + lane;
  float a0 = 0.f, a1 = 0.f;
#pragma unroll
  for (int jj = 0; jj < 16; ++jj) {
    int j = w * 16 + jj;
    float hj = hh[j];
    a0 = fmaf(hj, hyp_w2[j * W2COL + o0], a0);
    a1 = fmaf(hj, hyp_w2[j * W2COL + o0 + 128], a1);
  }
  part[w][0][lane] = a0;
  part[w][1][lane] = a1;
  __syncthreads();
  if (t < 64) {
    int c = cbase + t;                   // weff col (= GEMM n index)
    float h0 = part[0][0][t] + part[1][0][t] + part[2][0][t] + part[3][0][t]
               + hyp_b2[i * 256 + c];
    float h1 = part[0][1][t] + part[1][1][t] + part[2][1][t] + part[3][1][t]
               + hyp_b2[i * 256 + c + 128];
    float m0 = merger_w[c], m1 = merger_w[128 + c];
    float mx = fmaxf(m0, m1);
    float e0 = expf(m0 - mx), e1 = expf(m1 - mx);
    float val = (e0 * h0 + e1 * h1) / (e0 + e1);
    int unit = FB_WE + ((i >> 5) * 8 + (c >> 4)) * 64 + ((i >> 3) & 3) * 16 + (c & 15);
    wp[(size_t)unit * 8 + (i & 7)] = f2bf(val);
  }
}

// ---------------- K1: fused qphi + fc1 -> emb -> GRU -> fc2 -> sort ---------
__global__ __launch_bounds__(256) void k_main(
    const float* __restrict__ inp, const float* __restrict__ hprev,
    const float* __restrict__ rnd, const float* __restrict__ fc1_b,
    const unsigned short* __restrict__ wp,
    const float* __restrict__ gru_bi, const float* __restrict__ gru_bh,
    const float* __restrict__ phi_b, const float* __restrict__ fc2_b,
    float* __restrict__ h_out, float* __restrict__ q_out,
    float* __restrict__ rq_out) {
  __shared__ __align__(16) char smem[SM_TOTAL];
  unsigned short (*lds_in)[64][8] = (unsigned short(*)[64][8])(smem + SM_IN);
  unsigned short (*lds_x1)[64][8] = (unsigned short(*)[64][8])(smem + SM_X1);
  unsigned short (*lds_x2)[64][8] = (unsigned short(*)[64][8])(smem + SM_X2);
  unsigned short (*lds_h)[64][8]  = (unsigned short(*)[64][8])(smem + SM_H);
  float (*lds_hf)[132]            = (float(*)[132])(smem + SM_HF);
  unsigned short (*lds_qp)[136]   = (unsigned short(*)[136])(smem + SM_QP);
  float* lds_part                 = (float*)(smem + SM_PART);

  int t = threadIdx.x;
  int b0 = blockIdx.x * 16;
  int lane = t & 63, w = t >> 6;
  int quad = lane >> 4, l16 = lane & 15;
  int nt0 = w * 2;

  // ======== early issue: all global loads whose latency we can bury ========
  // Prefetch B-frags (grid=256 -> 1 wave/SIMD; VGPRs are effectively free,
  // and __syncthreads is a fence the compiler can't hoist loads across).
  short8 bPhi[2][2], bW1[8][2], bWE[4][2];
#pragma unroll
  for (int kt = 0; kt < 2; ++kt)
#pragma unroll
    for (int ni = 0; ni < 2; ++ni)
      bPhi[kt][ni] = *(const short8*)(wp +
          ((size_t)(FB_PHI + (kt * 8 + nt0 + ni) * 64 + lane)) * 8);
#pragma unroll
  for (int kt = 0; kt < 8; ++kt)
#pragma unroll
    for (int ni = 0; ni < 2; ++ni)
      bW1[kt][ni] = *(const short8*)(wp +
          ((size_t)(FB_W1 + (kt * 8 + nt0 + ni) * 64 + lane)) * 8);
#pragma unroll
  for (int kt = 0; kt < 4; ++kt)
#pragma unroll
    for (int ni = 0; ni < 2; ++ni)
      bWE[kt][ni] = *(const short8*)(wp +
          ((size_t)(FB_WE + (kt * 8 + nt0 + ni) * 64 + lane)) * 8);

  if (t < 16) rq_out[b0 + t] = rnd[b0 + t];

  // ---- stage In[16x256] -> bf16 A-frag LDS
#pragma unroll
  for (int i = 0; i < 2; ++i) {
    int idx = i * 256 + t;
    int oct = idx & 31, m = idx >> 5;
    const float* p = inp + (size_t)(b0 + m) * E_DIM + oct * 8;
    floatx4 v0 = *(const floatx4*)p;
    floatx4 v1 = *(const floatx4*)(p + 4);
    short8 pk;
    pk[0] = (short)f2bf(v0.x); pk[1] = (short)f2bf(v0.y);
    pk[2] = (short)f2bf(v0.z); pk[3] = (short)f2bf(v0.w);
    pk[4] = (short)f2bf(v1.x); pk[5] = (short)f2bf(v1.y);
    pk[6] = (short)f2bf(v1.z); pk[7] = (short)f2bf(v1.w);
    *(short8*)&lds_in[oct >> 2][(oct & 3) * 16 + m][0] = pk;
  }
  // ---- stage hprev[16x128] -> bf16 A-frag LDS
  {
    int oct = t & 15, m = t >> 4;
    const float* p = hprev + (size_t)(b0 + m) * H_DIM + oct * 8;
    floatx4 v0 = *(const floatx4*)p;
    floatx4 v1 = *(const floatx4*)(p + 4);
    short8 pk;
    pk[0] = (short)f2bf(v0.x); pk[1] = (short)f2bf(v0.y);
    pk[2] = (short)f2bf(v0.z); pk[3] = (short)f2bf(v0.w);
    pk[4] = (short)f2bf(v1.x); pk[5] = (short)f2bf(v1.y);
    pk[6] = (short)f2bf(v1.z); pk[7] = (short)f2bf(v1.w);
    *(short8*)&lds_h[oct >> 2][(oct & 3) * 16 + m][0] = pk;
  }

  // ---- phi: qp[m_qp][col] = relu(cos(pi*f*rq) @ phi_w + b), MFMA, M=16,K=64
  {
    float rqv = rnd[b0 + l16];           // row m_qp = l16 <-> rnd[blk*16+m_qp]
    short8 aC[2];
#pragma unroll
    for (int kt = 0; kt < 2; ++kt) {
#pragma unroll
      for (int j = 0; j < 8; ++j) {
        float f = (float)(kt * 32 + quad * 8 + j);
        aC[kt][j] = (short)f2bf(__cosf(3.14159265358979f * f * rqv));
      }
    }
    floatx4 cP[2] = {{0.f,0.f,0.f,0.f},{0.f,0.f,0.f,0.f}};
#pragma unroll
    for (int kt = 0; kt < 2; ++kt)
#pragma unroll
      for (int ni = 0; ni < 2; ++ni)
        cP[ni] = __builtin_amdgcn_mfma_f32_16x16x32_bf16(aC[kt], bPhi[kt][ni], cP[ni], 0, 0, 0);
#pragma unroll
    for (int ni = 0; ni < 2; ++ni) {
      int col = (nt0 + ni) * 16 + l16;
      float bias = phi_b[col];
#pragma unroll
      for (int reg = 0; reg < 4; ++reg) {
        int m_qp = quad * 4 + reg;
        lds_qp[m_qp][col] = f2bf(fmaxf(cP[ni][reg] + bias, 0.f));
      }
    }
  }
  __syncthreads();

  // ---- fc1: X1 = relu(In @ W1 + b)
  {
    short8 aIn[8];
#pragma unroll
    for (int kt = 0; kt < 8; ++kt)
      aIn[kt] = *(const short8*)&lds_in[kt][lane][0];
    floatx4 c1[2] = {{0.f,0.f,0.f,0.f},{0.f,0.f,0.f,0.f}};
#pragma unroll
    for (int kt = 0; kt < 8; ++kt)
#pragma unroll
      for (int n = 0; n < 2; ++n)
        c1[n] = __builtin_amdgcn_mfma_f32_16x16x32_bf16(aIn[kt], bW1[kt][n], c1[n], 0, 0, 0);
#pragma unroll
    for (int n = 0; n < 2; ++n) {
      int col = (nt0 + n) * 16 + l16;
      float bias = fc1_b[col];
#pragma unroll
      for (int reg = 0; reg < 4; ++reg) {
        float v = fmaxf(c1[n][reg] + bias, 0.f);
        lds_x1[col >> 5][((col >> 3) & 3) * 16 + quad * 4 + reg][col & 7] = f2bf(v);
      }
    }
  }
  __syncthreads();

  // ---- emb: X2 = relu(X1 @ Weff)
  {
    short8 a2[4];
#pragma unroll
    for (int kt = 0; kt < 4; ++kt)
      a2[kt] = *(const short8*)&lds_x1[kt][lane][0];
    floatx4 c2[2] = {{0.f,0.f,0.f,0.f},{0.f,0.f,0.f,0.f}};
#pragma unroll
    for (int kt = 0; kt < 4; ++kt)
#pragma unroll
      for (int n = 0; n < 2; ++n)
        c2[n] = __builtin_amdgcn_mfma_f32_16x16x32_bf16(a2[kt], bWE[kt][n], c2[n], 0, 0, 0);
#pragma unroll
    for (int n = 0; n < 2; ++n) {
      int col = (nt0 + n) * 16 + l16;
#pragma unroll
      for (int reg = 0; reg < 4; ++reg) {
        float v = fmaxf(c2[n][reg], 0.f);
        lds_x2[col >> 5][((col >> 3) & 3) * 16 + quad * 4 + reg][col & 7] = f2bf(v);
      }
    }
  }
  __syncthreads();

  // ---- GRU: column tiles {w, w+4}; writes h_out (global) + lds_hf (f32)
  {
    short8 ax[4], ah[4];
#pragma unroll
    for (int kt = 0; kt < 4; ++kt) {
      ax[kt] = *(const short8*)&lds_x2[kt][lane][0];
      ah[kt] = *(const short8*)&lds_h[kt][lane][0];
    }
#pragma unroll
    for (int cti = 0; cti < 2; ++cti) {
      int ct = w + cti * 4;
      floatx4 giR = {0.f,0.f,0.f,0.f}, giZ = {0.f,0.f,0.f,0.f}, giN = {0.f,0.f,0.f,0.f};
      floatx4 ghR = {0.f,0.f,0.f,0.f}, ghZ = {0.f,0.f,0.f,0.f}, ghN = {0.f,0.f,0.f,0.f};
#pragma unroll
      for (int kt = 0; kt < 4; ++kt) {
        short8 bR = *(const short8*)(wp + ((size_t)(FB_WI + (kt * 24 + ct) * 64 + lane)) * 8);
        short8 bZ = *(const short8*)(wp + ((size_t)(FB_WI + (kt * 24 + ct + 8) * 64 + lane)) * 8);
        short8 bN = *(const short8*)(wp + ((size_t)(FB_WI + (kt * 24 + ct + 16) * 64 + lane)) * 8);
        short8 cR = *(const short8*)(wp + ((size_t)(FB_WH + (kt * 24 + ct) * 64 + lane)) * 8);
        short8 cZ = *(const short8*)(wp + ((size_t)(FB_WH + (kt * 24 + ct + 8) * 64 + lane)) * 8);
        short8 cN = *(const short8*)(wp + ((size_t)(FB_WH + (kt * 24 + ct + 16) * 64 + lane)) * 8);
        giR = __builtin_amdgcn_mfma_f32_16x16x32_bf16(ax[kt], bR, giR, 0, 0, 0);
        giZ = __builtin_amdgcn_mfma_f32_16x16x32_bf16(ax[kt], bZ, giZ, 0, 0, 0);
        giN = __builtin_amdgcn_mfma_f32_16x16x32_bf16(ax[kt], bN, giN, 0, 0, 0);
        ghR = __builtin_amdgcn_mfma_f32_16x16x32_bf16(ah[kt], cR, ghR, 0, 0, 0);
        ghZ = __builtin_amdgcn_mfma_f32_16x16x32_bf16(ah[kt], cZ, ghZ, 0, 0, 0);
        ghN = __builtin_amdgcn_mfma_f32_16x16x32_bf16(ah[kt], cN, ghN, 0, 0, 0);
      }
      int c = ct * 16 + l16;
      float bir = gru_bi[c], biz = gru_bi[128 + c], bin = gru_bi[256 + c];
      float bhr = gru_bh[c], bhz = gru_bh[128 + c], bhn = gru_bh[256 + c];
#pragma unroll
      for (int reg = 0; reg < 4; ++reg) {
        int rl = quad * 4 + reg;
        int row = b0 + rl;
        float r = fsigmoid(giR[reg] + bir + ghR[reg] + bhr);
        float z = fsigmoid(giZ[reg] + biz + ghZ[reg] + bhz);
        float n = ftanh(giN[reg] + bin + r * (ghN[reg] + bhn));
        float hp = hprev[(size_t)row * H_DIM + c];
        float hv = (1.f - z) * n + z * hp;
        h_out[(size_t)row * H_DIM + c] = hv;
        lds_hf[rl][c] = hv;
      }
    }
  }
  __syncthreads();

  // ---- fc2 via MFMA, K split across waves (wave w owns k-slice w*32..+31)
  {
    int m = l16;                         // sample (A row)
    int k0 = w * 32 + quad * 8;
    const float* hptr = &lds_hf[m][k0];
    floatx4 h0 = *(const floatx4*)hptr;
    floatx4 h1 = *(const floatx4*)(hptr + 4);
    float hf[8] = {h0.x, h0.y, h0.z, h0.w, h1.x, h1.y, h1.z, h1.w};
    short8 bF = *(const short8*)(wp + ((size_t)(FB_FC2 + w * 64 + lane)) * 8);
    int qbase = (m >> 3) * 8;
    floatx4 cQ[8];
#pragma unroll
    for (int q = 0; q < NQv; ++q) cQ[q] = (floatx4){0.f,0.f,0.f,0.f};
#pragma unroll
    for (int q = 0; q < NQv; ++q) {
      short8 qpv = *(const short8*)&lds_qp[qbase + q][k0];
      short8 au;
#pragma unroll
      for (int j = 0; j < 8; ++j)
        au[j] = (short)f2bf(hf[j] * bf2f((unsigned short)qpv[j]));
      cQ[q] = __builtin_amdgcn_mfma_f32_16x16x32_bf16(au, bF, cQ[q], 0, 0, 0);
    }
#pragma unroll
    for (int q = 0; q < NQv; ++q)
      *(floatx4*)&lds_part[((w * 8 + q) * 64 + lane) * 4] = cQ[q];
  }
  __syncthreads();

  // ---- cross-wave K-reduce + bias + sort + store
  {
    int s = t >> 4, a = t & 15;
    int pl = (s >> 2) * 16 + a;          // C-layout lane for row s
    int pr = s & 3;                      // C-layout reg for row s
    float bias = (a < NAv) ? fc2_b[a] : 0.f;
    float qv[NQv];
#pragma unroll
    for (int q = 0; q < NQv; ++q) {
      float acc = bias;
#pragma unroll
      for (int ww = 0; ww < 4; ++ww)
        acc += lds_part[((ww * 8 + q) * 64 + pl) * 4 + pr];
      qv[q] = acc;
    }
#define CE(i, j) { float lo_ = fminf(qv[i], qv[j]); float hi_ = fmaxf(qv[i], qv[j]); qv[i] = lo_; qv[j] = hi_; }
    CE(0,1) CE(2,3) CE(4,5) CE(6,7)
    CE(0,2) CE(1,3) CE(4,6) CE(5,7)
    CE(1,2) CE(5,6)
    CE(0,4) CE(1,5) CE(2,6) CE(3,7)
    CE(2,4) CE(3,5)
    CE(1,2) CE(3,4) CE(5,6)
#undef CE
    if (a < NAv) {
      float4* o4 = (float4*)(q_out + (size_t)((b0 + s) * NAv + a) * NQv);
      o4[0] = make_float4(qv[0], qv[1], qv[2], qv[3]);
      o4[1] = make_float4(qv[4], qv[5], qv[6], qv[7]);
    }
  }
}

extern "C" void kernel_launch(void* const* d_in, const int* in_sizes, int n_in,
                              void* d_out, int out_size, void* d_ws, size_t ws_size,
                              hipStream_t stream) {
  (void)in_sizes; (void)n_in; (void)out_size; (void)ws_size;
  const float* inp      = (const float*)d_in[0];
  const float* hidden   = (const float*)d_in[1];
  const float* rnd      = (const float*)d_in[2];
  const float* fc1_w    = (const float*)d_in[3];
  const float* fc1_b    = (const float*)d_in[4];
  const float* hyp_w1   = (const float*)d_in[5];
  const float* hyp_b1   = (const float*)d_in[6];
  const float* hyp_w2   = (const float*)d_in[7];
  const float* hyp_b2   = (const float*)d_in[8];
  const float* merger_w = (const float*)d_in[9];
  const float* gru_wi   = (const float*)d_in[10];
  const float* gru_wh   = (const float*)d_in[11];
  const float* gru_bi   = (const float*)d_in[12];
  const float* gru_bh   = (const float*)d_in[13];
  const float* phi_w    = (const float*)d_in[14];
  const float* phi_b    = (const float*)d_in[15];
  const float* fc2_w    = (const float*)d_in[16];
  const float* fc2_b    = (const float*)d_in[17];
  float* out  = (float*)d_out;
  unsigned short* wp = (unsigned short*)d_ws;
  float* h_out = out + OUT_H_OFF;

  k_prep<<<dim3(PACK_BLOCKS + WEFF_BLOCKS), dim3(256), 0, stream>>>(
      fc1_w, gru_wi, gru_wh, phi_w, fc2_w,
      hyp_w1, hyp_b1, hyp_w2, hyp_b2, merger_w, wp);
  k_main<<<dim3(256), dim3(256), 0, stream>>>(inp, hidden, rnd, fc1_b, wp,
                                              gru_bi, gru_bh, phi_b, fc2_b,
                                              h_out, out, out + OUT_RQ_OFF);
}

// Round 5
// 104.898 us; speedup vs baseline: 1.6904x; 1.0215x over previous
//
#include <hip/hip_runtime.h>
#include <math.h>

typedef __attribute__((ext_vector_type(8))) short short8;
typedef __attribute__((ext_vector_type(4))) float floatx4;

#define E_DIM 256
#define H_DIM 128
#define NQv 8
#define QEDv 64
#define HYPv 64
#define NAv 14
#define NAGv 8
#define W2COL 32768   // H*H*HEADS

#define OUT_H_OFF 458752
#define OUT_RQ_OFF 983040

// packed frag units (unit = one lane-slot of 8 bf16; frag = 64 units)
#define FB_W1  0                // fc1:  8kt x 8nt  -> 4096 units
#define FB_WE  4096             // weff: 4kt x 8nt  -> 2048 units (written by weff part)
#define FB_WI  6144             // gru_wi^T: 4kt x 24nt -> 6144 units
#define FB_WH  12288            // gru_wh^T: 4kt x 24nt -> 6144 units
#define FB_PHI 18432            // phi_w: 2kt x 8nt -> 1024 units
#define FB_FC2 19456            // fc2_w (N pad 16): 4kt x 1nt -> 256 units
#define PACK_UNITS 17664        // pack part covers all but FB_WE
#define PACK_BLOCKS 69          // ceil(17664/256)
#define WEFF_BLOCKS 256

// shared-memory layout for k_main (bytes). lds_part now has its OWN region so
// the GRU->fc2 barrier can be dropped (no overlay race with staging buffers).
#define SM_IN   0               // ushort [8][64][8]  = 8192   (A-frags of In)
#define SM_X1   8192            // ushort [4][64][8]  = 4096
#define SM_X2   12288           // ushort [4][64][8]  = 4096
#define SM_H    16384           // ushort [4][64][8]  = 4096
#define SM_HF   20480           // float  [16][132]   = 8448
#define SM_QP   28928           // ushort [16][136]   = 4352
#define SM_PART 33280           // float  [4][8][64][4] = 32768
#define SM_TOTAL 66048

__device__ __forceinline__ unsigned short f2bf(float x) {
  unsigned u = __builtin_bit_cast(unsigned, x);
  u += 0x7FFFu + ((u >> 16) & 1u);
  return (unsigned short)(u >> 16);
}
__device__ __forceinline__ float bf2f(unsigned short s) {
  return __builtin_bit_cast(float, ((unsigned)s) << 16);
}
__device__ __forceinline__ float fsigmoid(float x) {
  return 1.f / (1.f + __expf(-x));
}
__device__ __forceinline__ float ftanh(float x) {
  float t = __expf(-2.f * x);
  return (1.f - t) / (1.f + t);
}

// ---------------- K0: fused weight prep (pack + hypernet W_eff) -------------
// blocks [0, PACK_BLOCKS): pack static weights into MFMA B-frag bf16.
// blocks [PACK_BLOCKS, PACK_BLOCKS+WEFF_BLOCKS): hypernet -> W_eff B-frags.
// prev == ones => hypernet output is sample-independent; merger softmax folded.
__global__ __launch_bounds__(256) void k_prep(
    const float* __restrict__ fc1_w, const float* __restrict__ gru_wi,
    const float* __restrict__ gru_wh, const float* __restrict__ phi_w,
    const float* __restrict__ fc2_w,
    const float* __restrict__ hyp_w1, const float* __restrict__ hyp_b1,
    const float* __restrict__ hyp_w2, const float* __restrict__ hyp_b2,
    const float* __restrict__ merger_w, unsigned short* __restrict__ wp) {
  __shared__ float hh[HYPv];
  __shared__ float part[4][2][64];
  int t = threadIdx.x;

  if (blockIdx.x < PACK_BLOCKS) {
    // ---------------- pack branch ----------------
    int u = blockIdx.x * 256 + t;
    if (u >= PACK_UNITS) return;
    float v[8];
    int f;
    if (u < 4096) {                      // fc1_w [256x128], B[k][n]=w[k*128+n]
      int g = u, nt = (g >> 6) & 7, lane = g & 63;
      int k0 = (g >> 9) * 32 + ((lane >> 4) << 3), n = nt * 16 + (lane & 15);
      f = FB_W1 + g;
#pragma unroll
      for (int j = 0; j < 8; ++j) v[j] = fc1_w[(k0 + j) * H_DIM + n];
    } else if (u < 10240) {              // gru_wi [384x128], B[k][g]=wi[g*128+k]
      int g = u - 4096, kt = g / 1536, rem = g % 1536, nt = rem >> 6, lane = rem & 63;
      int k0 = kt * 32 + ((lane >> 4) << 3), n = nt * 16 + (lane & 15);
      f = FB_WI + g;
#pragma unroll
      for (int j = 0; j < 8; ++j) v[j] = gru_wi[n * H_DIM + k0 + j];
    } else if (u < 16384) {              // gru_wh
      int g = u - 10240, kt = g / 1536, rem = g % 1536, nt = rem >> 6, lane = rem & 63;
      int k0 = kt * 32 + ((lane >> 4) << 3), n = nt * 16 + (lane & 15);
      f = FB_WH + g;
#pragma unroll
      for (int j = 0; j < 8; ++j) v[j] = gru_wh[n * H_DIM + k0 + j];
    } else if (u < 17408) {              // phi_w [64x128], B[k][n]=w[k*128+n]
      int g = u - 16384, kt = g >> 9, nt = (g >> 6) & 7, lane = g & 63;
      int k0 = kt * 32 + ((lane >> 4) << 3), n = nt * 16 + (lane & 15);
      f = FB_PHI + g;
#pragma unroll
      for (int j = 0; j < 8; ++j) v[j] = phi_w[(k0 + j) * H_DIM + n];
    } else {                             // fc2_w [128x14], pad N to 16
      int g = u - 17408, kt = g >> 6, lane = g & 63;
      int k0 = kt * 32 + ((lane >> 4) << 3), n = lane & 15;
      f = FB_FC2 + g;
#pragma unroll
      for (int j = 0; j < 8; ++j) v[j] = (n < NAv) ? fc2_w[(k0 + j) * NAv + n] : 0.f;
    }
    short8 pk;
#pragma unroll
    for (int j = 0; j < 8; ++j) pk[j] = (short)f2bf(v[j]);
    *(short8*)(wp + (size_t)f * 8) = pk;
    return;
  }

  // ---------------- weff branch ----------------
  int blk = blockIdx.x - PACK_BLOCKS;
  if (t < HYPv) {
    float s = hyp_b1[t];
#pragma unroll
    for (int i = 0; i < NQv; ++i) s += hyp_w1[i * HYPv + t];
    hh[t] = fmaxf(s, 0.f);
  }
  __syncthreads();
  int w = t >> 6, lane = t & 63;
  int i = blk >> 1;                      // weff row (= GEMM k index)
  int cbase = (blk & 1) * 64;
  int o0 = i * 256 + cbase + lane;
  float a0 = 0.f, a1 = 0.f;
#pragma unroll
  for (int jj = 0; jj < 16; ++jj) {
    int j = w * 16 + jj;
    float hj = hh[j];
    a0 = fmaf(hj, hyp_w2[j * W2COL + o0], a0);
    a1 = fmaf(hj, hyp_w2[j * W2COL + o0 + 128], a1);
  }
  part[w][0][lane] = a0;
  part[w][1][lane] = a1;
  __syncthreads();
  if (t < 64) {
    int c = cbase + t;                   // weff col (= GEMM n index)
    float h0 = part[0][0][t] + part[1][0][t] + part[2][0][t] + part[3][0][t]
               + hyp_b2[i * 256 + c];
    float h1 = part[0][1][t] + part[1][1][t] + part[2][1][t] + part[3][1][t]
               + hyp_b2[i * 256 + c + 128];
    float m0 = merger_w[c], m1 = merger_w[128 + c];
    float mx = fmaxf(m0, m1);
    float e0 = expf(m0 - mx), e1 = expf(m1 - mx);
    float val = (e0 * h0 + e1 * h1) / (e0 + e1);
    int unit = FB_WE + ((i >> 5) * 8 + (c >> 4)) * 64 + ((i >> 3) & 3) * 16 + (c & 15);
    wp[(size_t)unit * 8 + (i & 7)] = f2bf(val);
  }
}

// ---------------- K1: fused qphi + fc1 -> emb -> GRU -> fc2 -> sort ---------
__global__ __launch_bounds__(256) void k_main(
    const float* __restrict__ inp, const float* __restrict__ hprev,
    const float* __restrict__ rnd, const float* __restrict__ fc1_b,
    const unsigned short* __restrict__ wp,
    const float* __restrict__ gru_bi, const float* __restrict__ gru_bh,
    const float* __restrict__ phi_b, const float* __restrict__ fc2_b,
    float* __restrict__ h_out, float* __restrict__ q_out,
    float* __restrict__ rq_out) {
  __shared__ __align__(16) char smem[SM_TOTAL];
  unsigned short (*lds_in)[64][8] = (unsigned short(*)[64][8])(smem + SM_IN);
  unsigned short (*lds_x1)[64][8] = (unsigned short(*)[64][8])(smem + SM_X1);
  unsigned short (*lds_x2)[64][8] = (unsigned short(*)[64][8])(smem + SM_X2);
  unsigned short (*lds_h)[64][8]  = (unsigned short(*)[64][8])(smem + SM_H);
  float (*lds_hf)[132]            = (float(*)[132])(smem + SM_HF);
  unsigned short (*lds_qp)[136]   = (unsigned short(*)[136])(smem + SM_QP);
  float* lds_part                 = (float*)(smem + SM_PART);

  int t = threadIdx.x;
  int b0 = blockIdx.x * 16;
  int lane = t & 63, w = t >> 6;
  int quad = lane >> 4, l16 = lane & 15;
  int nt0 = w * 2;

  // ======== early issue: all global loads whose latency we can bury ========
  // Prefetch B-frags (grid=256 -> 1 wave/SIMD; VGPRs are effectively free,
  // and __syncthreads is a fence the compiler can't hoist loads across).
  short8 bPhi[2][2], bW1[8][2], bWE[4][2], bF;
#pragma unroll
  for (int kt = 0; kt < 2; ++kt)
#pragma unroll
    for (int ni = 0; ni < 2; ++ni)
      bPhi[kt][ni] = *(const short8*)(wp +
          ((size_t)(FB_PHI + (kt * 8 + nt0 + ni) * 64 + lane)) * 8);
#pragma unroll
  for (int kt = 0; kt < 8; ++kt)
#pragma unroll
    for (int ni = 0; ni < 2; ++ni)
      bW1[kt][ni] = *(const short8*)(wp +
          ((size_t)(FB_W1 + (kt * 8 + nt0 + ni) * 64 + lane)) * 8);
#pragma unroll
  for (int kt = 0; kt < 4; ++kt)
#pragma unroll
    for (int ni = 0; ni < 2; ++ni)
      bWE[kt][ni] = *(const short8*)(wp +
          ((size_t)(FB_WE + (kt * 8 + nt0 + ni) * 64 + lane)) * 8);
  bF = *(const short8*)(wp + ((size_t)(FB_FC2 + w * 64 + lane)) * 8);

  if (t < 16) rq_out[b0 + t] = rnd[b0 + t];

  // ---- stage In[16x256] -> bf16 A-frag LDS
#pragma unroll
  for (int i = 0; i < 2; ++i) {
    int idx = i * 256 + t;
    int oct = idx & 31, m = idx >> 5;
    const float* p = inp + (size_t)(b0 + m) * E_DIM + oct * 8;
    floatx4 v0 = *(const floatx4*)p;
    floatx4 v1 = *(const floatx4*)(p + 4);
    short8 pk;
    pk[0] = (short)f2bf(v0.x); pk[1] = (short)f2bf(v0.y);
    pk[2] = (short)f2bf(v0.z); pk[3] = (short)f2bf(v0.w);
    pk[4] = (short)f2bf(v1.x); pk[5] = (short)f2bf(v1.y);
    pk[6] = (short)f2bf(v1.z); pk[7] = (short)f2bf(v1.w);
    *(short8*)&lds_in[oct >> 2][(oct & 3) * 16 + m][0] = pk;
  }
  // ---- stage hprev[16x128] -> bf16 A-frag LDS
  {
    int oct = t & 15, m = t >> 4;
    const float* p = hprev + (size_t)(b0 + m) * H_DIM + oct * 8;
    floatx4 v0 = *(const floatx4*)p;
    floatx4 v1 = *(const floatx4*)(p + 4);
    short8 pk;
    pk[0] = (short)f2bf(v0.x); pk[1] = (short)f2bf(v0.y);
    pk[2] = (short)f2bf(v0.z); pk[3] = (short)f2bf(v0.w);
    pk[4] = (short)f2bf(v1.x); pk[5] = (short)f2bf(v1.y);
    pk[6] = (short)f2bf(v1.z); pk[7] = (short)f2bf(v1.w);
    *(short8*)&lds_h[oct >> 2][(oct & 3) * 16 + m][0] = pk;
  }

  // ---- phi: qp[m_qp][col] = relu(cos(pi*f*rq) @ phi_w + b), MFMA, M=16,K=64
  // wave w writes lds_qp columns [32w, 32w+32) -- consumed by the SAME wave
  // in the fc2 section (no cross-wave dependency on lds_qp).
  {
    float rqv = rnd[b0 + l16];           // row m_qp = l16 <-> rnd[blk*16+m_qp]
    short8 aC[2];
#pragma unroll
    for (int kt = 0; kt < 2; ++kt) {
#pragma unroll
      for (int j = 0; j < 8; ++j) {
        float f = (float)(kt * 32 + quad * 8 + j);
        aC[kt][j] = (short)f2bf(__cosf(3.14159265358979f * f * rqv));
      }
    }
    floatx4 cP[2] = {{0.f,0.f,0.f,0.f},{0.f,0.f,0.f,0.f}};
#pragma unroll
    for (int kt = 0; kt < 2; ++kt)
#pragma unroll
      for (int ni = 0; ni < 2; ++ni)
        cP[ni] = __builtin_amdgcn_mfma_f32_16x16x32_bf16(aC[kt], bPhi[kt][ni], cP[ni], 0, 0, 0);
#pragma unroll
    for (int ni = 0; ni < 2; ++ni) {
      int col = (nt0 + ni) * 16 + l16;
      float bias = phi_b[col];
#pragma unroll
      for (int reg = 0; reg < 4; ++reg) {
        int m_qp = quad * 4 + reg;
        lds_qp[m_qp][col] = f2bf(fmaxf(cP[ni][reg] + bias, 0.f));
      }
    }
  }
  __syncthreads();   // B1: staging (lds_in / lds_h) is cross-wave

  // ---- fc1: X1 = relu(In @ W1 + b)
  {
    short8 aIn[8];
#pragma unroll
    for (int kt = 0; kt < 8; ++kt)
      aIn[kt] = *(const short8*)&lds_in[kt][lane][0];
    floatx4 c1[2] = {{0.f,0.f,0.f,0.f},{0.f,0.f,0.f,0.f}};
#pragma unroll
    for (int kt = 0; kt < 8; ++kt)
#pragma unroll
      for (int n = 0; n < 2; ++n)
        c1[n] = __builtin_amdgcn_mfma_f32_16x16x32_bf16(aIn[kt], bW1[kt][n], c1[n], 0, 0, 0);
#pragma unroll
    for (int n = 0; n < 2; ++n) {
      int col = (nt0 + n) * 16 + l16;
      float bias = fc1_b[col];
#pragma unroll
      for (int reg = 0; reg < 4; ++reg) {
        float v = fmaxf(c1[n][reg] + bias, 0.f);
        lds_x1[col >> 5][((col >> 3) & 3) * 16 + quad * 4 + reg][col & 7] = f2bf(v);
      }
    }
  }
  __syncthreads();   // B2: x1 cross-wave

  // prefetch GRU cti=0 B-frags; latency buried under the emb MFMAs below
  short8 pGi[4][3], pGh[4][3];
  {
    int ct = 2 * w;
#pragma unroll
    for (int kt = 0; kt < 4; ++kt) {
#pragma unroll
      for (int g = 0; g < 3; ++g) {
        pGi[kt][g] = *(const short8*)(wp + ((size_t)(FB_WI + (kt * 24 + ct + g * 8) * 64 + lane)) * 8);
        pGh[kt][g] = *(const short8*)(wp + ((size_t)(FB_WH + (kt * 24 + ct + g * 8) * 64 + lane)) * 8);
      }
    }
  }

  // ---- emb: X2 = relu(X1 @ Weff)
  {
    short8 a2[4];
#pragma unroll
    for (int kt = 0; kt < 4; ++kt)
      a2[kt] = *(const short8*)&lds_x1[kt][lane][0];
    floatx4 c2[2] = {{0.f,0.f,0.f,0.f},{0.f,0.f,0.f,0.f}};
#pragma unroll
    for (int kt = 0; kt < 4; ++kt)
#pragma unroll
      for (int n = 0; n < 2; ++n)
        c2[n] = __builtin_amdgcn_mfma_f32_16x16x32_bf16(a2[kt], bWE[kt][n], c2[n], 0, 0, 0);
#pragma unroll
    for (int n = 0; n < 2; ++n) {
      int col = (nt0 + n) * 16 + l16;
#pragma unroll
      for (int reg = 0; reg < 4; ++reg) {
        float v = fmaxf(c2[n][reg], 0.f);
        lds_x2[col >> 5][((col >> 3) & 3) * 16 + quad * 4 + reg][col & 7] = f2bf(v);
      }
    }
  }
  __syncthreads();   // B3: x2 cross-wave

  // ---- GRU: wave w produces h columns [32w, 32w+32) = exactly the K-slice
  // its own fc2 section consumes -> no barrier between GRU and fc2.
  {
    short8 ax[4], ah[4];
#pragma unroll
    for (int kt = 0; kt < 4; ++kt) {
      ax[kt] = *(const short8*)&lds_x2[kt][lane][0];
      ah[kt] = *(const short8*)&lds_h[kt][lane][0];
    }
#pragma unroll
    for (int cti = 0; cti < 2; ++cti) {
      int ct = 2 * w + cti;
      floatx4 giR = {0.f,0.f,0.f,0.f}, giZ = {0.f,0.f,0.f,0.f}, giN = {0.f,0.f,0.f,0.f};
      floatx4 ghR = {0.f,0.f,0.f,0.f}, ghZ = {0.f,0.f,0.f,0.f}, ghN = {0.f,0.f,0.f,0.f};
#pragma unroll
      for (int kt = 0; kt < 4; ++kt) {
        short8 bR, bZ, bN, cR, cZ, cN;
        if (cti == 0) {
          bR = pGi[kt][0]; bZ = pGi[kt][1]; bN = pGi[kt][2];
          cR = pGh[kt][0]; cZ = pGh[kt][1]; cN = pGh[kt][2];
        } else {
          bR = *(const short8*)(wp + ((size_t)(FB_WI + (kt * 24 + ct) * 64 + lane)) * 8);
          bZ = *(const short8*)(wp + ((size_t)(FB_WI + (kt * 24 + ct + 8) * 64 + lane)) * 8);
          bN = *(const short8*)(wp + ((size_t)(FB_WI + (kt * 24 + ct + 16) * 64 + lane)) * 8);
          cR = *(const short8*)(wp + ((size_t)(FB_WH + (kt * 24 + ct) * 64 + lane)) * 8);
          cZ = *(const short8*)(wp + ((size_t)(FB_WH + (kt * 24 + ct + 8) * 64 + lane)) * 8);
          cN = *(const short8*)(wp + ((size_t)(FB_WH + (kt * 24 + ct + 16) * 64 + lane)) * 8);
        }
        giR = __builtin_amdgcn_mfma_f32_16x16x32_bf16(ax[kt], bR, giR, 0, 0, 0);
        giZ = __builtin_amdgcn_mfma_f32_16x16x32_bf16(ax[kt], bZ, giZ, 0, 0, 0);
        giN = __builtin_amdgcn_mfma_f32_16x16x32_bf16(ax[kt], bN, giN, 0, 0, 0);
        ghR = __builtin_amdgcn_mfma_f32_16x16x32_bf16(ah[kt], cR, ghR, 0, 0, 0);
        ghZ = __builtin_amdgcn_mfma_f32_16x16x32_bf16(ah[kt], cZ, ghZ, 0, 0, 0);
        ghN = __builtin_amdgcn_mfma_f32_16x16x32_bf16(ah[kt], cN, ghN, 0, 0, 0);
      }
      int c = ct * 16 + l16;
      float bir = gru_bi[c], biz = gru_bi[128 + c], bin = gru_bi[256 + c];
      float bhr = gru_bh[c], bhz = gru_bh[128 + c], bhn = gru_bh[256 + c];
#pragma unroll
      for (int reg = 0; reg < 4; ++reg) {
        int rl = quad * 4 + reg;
        int row = b0 + rl;
        float r = fsigmoid(giR[reg] + bir + ghR[reg] + bhr);
        float z = fsigmoid(giZ[reg] + biz + ghZ[reg] + bhz);
        float n = ftanh(giN[reg] + bin + r * (ghN[reg] + bhn));
        float hp = hprev[(size_t)row * H_DIM + c];
        float hv = (1.f - z) * n + z * hp;
        h_out[(size_t)row * H_DIM + c] = hv;
        lds_hf[rl][c] = hv;
      }
    }
  }
  // no barrier: fc2 below reads only lds_hf/lds_qp columns this wave wrote

  // ---- fc2 via MFMA, K split across waves (wave w owns k-slice w*32..+31)
  {
    int m = l16;                         // sample (A row)
    int k0 = w * 32 + quad * 8;
    const float* hptr = &lds_hf[m][k0];
    floatx4 h0 = *(const floatx4*)hptr;
    floatx4 h1 = *(const floatx4*)(hptr + 4);
    float hf[8] = {h0.x, h0.y, h0.z, h0.w, h1.x, h1.y, h1.z, h1.w};
    int qbase = (m >> 3) * 8;
    floatx4 cQ[8];
#pragma unroll
    for (int q = 0; q < NQv; ++q) cQ[q] = (floatx4){0.f,0.f,0.f,0.f};
#pragma unroll
    for (int q = 0; q < NQv; ++q) {
      short8 qpv = *(const short8*)&lds_qp[qbase + q][k0];
      short8 au;
#pragma unroll
      for (int j = 0; j < 8; ++j)
        au[j] = (short)f2bf(hf[j] * bf2f((unsigned short)qpv[j]));
      cQ[q] = __builtin_amdgcn_mfma_f32_16x16x32_bf16(au, bF, cQ[q], 0, 0, 0);
    }
#pragma unroll
    for (int q = 0; q < NQv; ++q)
      *(floatx4*)&lds_part[((w * 8 + q) * 64 + lane) * 4] = cQ[q];
  }
  __syncthreads();   // B4: cross-wave K-reduce

  // ---- cross-wave K-reduce + bias + sort + store
  {
    int s = t >> 4, a = t & 15;
    int pl = (s >> 2) * 16 + a;          // C-layout lane for row s
    int pr = s & 3;                      // C-layout reg for row s
    float bias = (a < NAv) ? fc2_b[a] : 0.f;
    float qv[NQv];
#pragma unroll
    for (int q = 0; q < NQv; ++q) {
      float acc = bias;
#pragma unroll
      for (int ww = 0; ww < 4; ++ww)
        acc += lds_part[((ww * 8 + q) * 64 + pl) * 4 + pr];
      qv[q] = acc;
    }
#define CE(i, j) { float lo_ = fminf(qv[i], qv[j]); float hi_ = fmaxf(qv[i], qv[j]); qv[i] = lo_; qv[j] = hi_; }
    CE(0,1) CE(2,3) CE(4,5) CE(6,7)
    CE(0,2) CE(1,3) CE(4,6) CE(5,7)
    CE(1,2) CE(5,6)
    CE(0,4) CE(1,5) CE(2,6) CE(3,7)
    CE(2,4) CE(3,5)
    CE(1,2) CE(3,4) CE(5,6)
#undef CE
    if (a < NAv) {
      float4* o4 = (float4*)(q_out + (size_t)((b0 + s) * NAv + a) * NQv);
      o4[0] = make_float4(qv[0], qv[1], qv[2], qv[3]);
      o4[1] = make_float4(qv[4], qv[5], qv[6], qv[7]);
    }
  }
}

extern "C" void kernel_launch(void* const* d_in, const int* in_sizes, int n_in,
                              void* d_out, int out_size, void* d_ws, size_t ws_size,
                              hipStream_t stream) {
  (void)in_sizes; (void)n_in; (void)out_size; (void)ws_size;
  const float* inp      = (const float*)d_in[0];
  const float* hidden   = (const float*)d_in[1];
  const float* rnd      = (const float*)d_in[2];
  const float* fc1_w    = (const float*)d_in[3];
  const float* fc1_b    = (const float*)d_in[4];
  const float* hyp_w1   = (const float*)d_in[5];
  const float* hyp_b1   = (const float*)d_in[6];
  const float* hyp_w2   = (const float*)d_in[7];
  const float* hyp_b2   = (const float*)d_in[8];
  const float* merger_w = (const float*)d_in[9];
  const float* gru_wi   = (const float*)d_in[10];
  const float* gru_wh   = (const float*)d_in[11];
  const float* gru_bi   = (const float*)d_in[12];
  const float* gru_bh   = (const float*)d_in[13];
  const float* phi_w    = (const float*)d_in[14];
  const float* phi_b    = (const float*)d_in[15];
  const float* fc2_w    = (const float*)d_in[16];
  const float* fc2_b    = (const float*)d_in[17];
  float* out  = (float*)d_out;
  unsigned short* wp = (unsigned short*)d_ws;
  float* h_out = out + OUT_H_OFF;

  k_prep<<<dim3(PACK_BLOCKS + WEFF_BLOCKS), dim3(256), 0, stream>>>(
      fc1_w, gru_wi, gru_wh, phi_w, fc2_w,
      hyp_w1, hyp_b1, hyp_w2, hyp_b2, merger_w, wp);
  k_main<<<dim3(256), dim3(256), 0, stream>>>(inp, hidden, rnd, fc1_b, wp,
                                              gru_bi, gru_bh, phi_b, fc2_b,
                                              h_out, out, out + OUT_RQ_OFF);
}